// Round 2
// baseline (3456.266 us; speedup 1.0000x reference)
//
#include <hip/hip_runtime.h>
#include <hip/hip_bf16.h>

typedef unsigned short u16;
typedef short bf16x8 __attribute__((ext_vector_type(8)));
typedef float f32x4 __attribute__((ext_vector_type(4)));
typedef float f32x16 __attribute__((ext_vector_type(16)));

#define DEV __device__ __forceinline__

DEV u16 f2bf(float f) {
  union { float f; unsigned u; } a; a.f = f;
  unsigned r = a.u + 0x7FFFu + ((a.u >> 16) & 1u);
  return (u16)(r >> 16);
}
DEV float bf2f(u16 u) {
  union { unsigned u; float f; } a; a.u = ((unsigned)u) << 16; return a.f;
}
DEV void async16(const void* g, void* l) {
  __builtin_amdgcn_global_load_lds(
      (const __attribute__((address_space(1))) unsigned int*)g,
      (__attribute__((address_space(3))) unsigned int*)l, 16, 0, 0);
}

// ---------------- transpose + cvt: in fp32 [K][N] -> out bf16 [N][K] ----------------
__global__ __launch_bounds__(256) void transpose_cvt(const float* __restrict__ in,
                                                     u16* __restrict__ out, int K, int N) {
  __shared__ float tile[32][33];
  const int kt = blockIdx.y * 32, nt = blockIdx.x * 32;
  const int tx = threadIdx.x & 31, ty = threadIdx.x >> 5;  // ty 0..7
#pragma unroll
  for (int i = 0; i < 32; i += 8) {
    int k = kt + ty + i, n = nt + tx;
    tile[ty + i][tx] = (k < K && n < N) ? in[(long)k * N + n] : 0.f;
  }
  __syncthreads();
#pragma unroll
  for (int i = 0; i < 32; i += 8) {
    int n = nt + ty + i, k = kt + tx;
    if (n < N && k < K) out[(long)n * K + k] = f2bf(tile[tx][ty + i]);
  }
}

// ---------------- prep: concat + clip -> bf16 x [R][768] ----------------
__global__ __launch_bounds__(256) void prep_kernel(const float* __restrict__ state,
                                                   const float* __restrict__ cond,
                                                   u16* __restrict__ xb) {
  int idx = blockIdx.x * 256 + threadIdx.x;           // R*192 quads exactly
  int t = idx / 192, c4 = idx - t * 192;
  float4 v;
  if (c4 < 128) v = ((const float4*)state)[(long)t * 128 + c4];
  else          v = ((const float4*)cond)[(long)t * 64 + (c4 - 128)];
  ushort4 o;
  o.x = f2bf(fminf(fmaxf(v.x, -16.f), 16.f));
  o.y = f2bf(fminf(fmaxf(v.y, -16.f), 16.f));
  o.z = f2bf(fminf(fmaxf(v.z, -16.f), 16.f));
  o.w = f2bf(fminf(fmaxf(v.w, -16.f), 16.f));
  *(ushort4*)(xb + (long)t * 768 + c4 * 4) = o;
}

// ---------------- block reduction (256 threads, 4 waves) ----------------
DEV void reduce2(float& s, float& q, float* sh, int tid) {
#pragma unroll
  for (int off = 32; off; off >>= 1) { s += __shfl_xor(s, off); q += __shfl_xor(q, off); }
  const int w = tid >> 6;
  if ((tid & 63) == 0) { sh[w] = s; sh[4 + w] = q; }
  __syncthreads();
  s = sh[0] + sh[1] + sh[2] + sh[3];
  q = sh[4] + sh[5] + sh[6] + sh[7];
}

// ---------------- LN (+ReLU) rowwise, H=1024 ----------------
__global__ __launch_bounds__(256) void ln_relu_kernel(const u16* __restrict__ in,
                                                      const float* __restrict__ g,
                                                      const float* __restrict__ bt,
                                                      u16* __restrict__ out) {
  __shared__ float sh[8];
  const long row = blockIdx.x;
  const int tid = threadIdx.x;
  ushort4 hv = *(const ushort4*)(in + row * 1024 + tid * 4);
  float x[4] = {bf2f(hv.x), bf2f(hv.y), bf2f(hv.z), bf2f(hv.w)};
  float s = x[0] + x[1] + x[2] + x[3];
  float q = x[0]*x[0] + x[1]*x[1] + x[2]*x[2] + x[3]*x[3];
  reduce2(s, q, sh, tid);
  float mean = s * (1.f / 1024.f);
  float var  = q * (1.f / 1024.f) - mean * mean;
  float rs   = rsqrtf(var + 1e-5f);
  ushort4 ov;
  u16* op = (u16*)&ov;
#pragma unroll
  for (int j = 0; j < 4; ++j) {
    int c = tid * 4 + j;
    float y = (x[j] - mean) * rs * g[c] + bt[c];
    op[j] = f2bf(fmaxf(y, 0.f));
  }
  *(ushort4*)(out + row * 1024 + tid * 4) = ov;
}

// ---------------- qin = LN(h)*gain + bias (gain/bias [row][1024]) ----------------
// NOTE: qout may alias gain (per-thread same-index element-wise) -> no restrict.
__global__ __launch_bounds__(256) void qin_kernel(const u16* __restrict__ h,
                                                  const u16* gain, const u16* bias,
                                                  const float* __restrict__ lg,
                                                  const float* __restrict__ lbt,
                                                  u16* qout) {
  __shared__ float sh[8];
  const long row = blockIdx.x;
  const int tid = threadIdx.x;
  ushort4 hv = *(const ushort4*)(h + row * 1024 + tid * 4);
  float x[4] = {bf2f(hv.x), bf2f(hv.y), bf2f(hv.z), bf2f(hv.w)};
  float s = x[0] + x[1] + x[2] + x[3];
  float q = x[0]*x[0] + x[1]*x[1] + x[2]*x[2] + x[3]*x[3];
  reduce2(s, q, sh, tid);
  float mean = s * (1.f / 1024.f);
  float var  = q * (1.f / 1024.f) - mean * mean;
  float rs   = rsqrtf(var + 1e-5f);
  ushort4 gv = *(const ushort4*)(gain + row * 1024 + tid * 4);
  ushort4 bv = *(const ushort4*)(bias + row * 1024 + tid * 4);
  const u16* gp = (const u16*)&gv;
  const u16* bp = (const u16*)&bv;
  ushort4 ov; u16* op = (u16*)&ov;
#pragma unroll
  for (int j = 0; j < 4; ++j) {
    int c = tid * 4 + j;
    float y = (x[j] - mean) * rs * lg[c] + lbt[c];
    op[j] = f2bf(y * bf2f(gp[j]) + bf2f(bp[j]));
  }
  *(ushort4*)(qout + row * 1024 + tid * 4) = ov;
}

// ---------------- h2 = LN(h + o2)  (o2 already includes res) ----------------
__global__ __launch_bounds__(256) void h2_kernel(const u16* __restrict__ h,
                                                 const u16* o2,
                                                 const float* __restrict__ g,
                                                 const float* __restrict__ bt,
                                                 u16* out) {
  __shared__ float sh[8];
  const long row = blockIdx.x;
  const int tid = threadIdx.x;
  ushort4 a = *(const ushort4*)(h  + row * 1024 + tid * 4);
  ushort4 b = *(const ushort4*)(o2 + row * 1024 + tid * 4);
  const u16* ap = (const u16*)&a; const u16* bp = (const u16*)&b;
  float x[4];
#pragma unroll
  for (int j = 0; j < 4; ++j) x[j] = bf2f(ap[j]) + bf2f(bp[j]);
  float s = x[0] + x[1] + x[2] + x[3];
  float q = x[0]*x[0] + x[1]*x[1] + x[2]*x[2] + x[3]*x[3];
  reduce2(s, q, sh, tid);
  float mean = s * (1.f / 1024.f);
  float var  = q * (1.f / 1024.f) - mean * mean;
  float rs   = rsqrtf(var + 1e-5f);
  ushort4 ov; u16* op = (u16*)&ov;
#pragma unroll
  for (int j = 0; j < 4; ++j) {
    int c = tid * 4 + j;
    op[j] = f2bf((x[j] - mean) * rs * g[c] + bt[c]);
  }
  *(ushort4*)(out + row * 1024 + tid * 4) = ov;
}

// ---------------- GEMM: A[M][K] bf16 (lda), Bt[N][K] bf16 -> C[M][N] ----------------
// EPI: 0=bias->bf16, 1=gelu->bf16, 2=1+0.5*tanh->bf16, 3=relu->bf16, 4=bias->f32,
//      5=+addend->bf16 (addend/Co may alias in-place), 6=0.5*tanh->bf16
template <int EPI>
__global__ __launch_bounds__(256) void gemm_bt(const u16* __restrict__ A,
                                               const u16* __restrict__ Bt,
                                               const float* __restrict__ bias,
                                               const u16* addend,
                                               u16* Co, float* Cf,
                                               int N, int K, int lda) {
  __shared__ u16 As[128 * 64];
  __shared__ u16 Bs[128 * 64];
  const int tid = threadIdx.x;
  const int w = tid >> 6, l = tid & 63;
  const int wr = w >> 1, wc = w & 1;
  const long bRow = (long)blockIdx.x * 128;
  const long bCol = (long)blockIdx.y * 128;

  f32x4 acc[4][4];
#pragma unroll
  for (int mi = 0; mi < 4; ++mi)
#pragma unroll
    for (int ni = 0; ni < 4; ++ni)
#pragma unroll
      for (int r = 0; r < 4; ++r) acc[mi][ni][r] = 0.f;

  const int arow = l >> 3;             // 0..7
  const int acol = (l & 7) * 8;        // 0..56
  const u16* gA = A + (bRow + w * 8 + arow) * (long)lda + acol;
  const u16* gB = Bt + (bCol + w * 8 + arow) * (long)K + acol;

  const int fr = l & 15;
  const int fks = (l >> 4) * 8;        // 0,8,16,24

  for (int kt = 0; kt < K; kt += 64) {
#pragma unroll
    for (int i = 0; i < 4; ++i) {
      async16(gA + (long)i * 32 * lda + kt, As + (i * 32 + w * 8) * 64);
      async16(gB + (long)i * 32 * K   + kt, Bs + (i * 32 + w * 8) * 64);
    }
    __syncthreads();
#pragma unroll
    for (int kk = 0; kk < 2; ++kk) {
      const int ko = kk * 32 + fks;
      bf16x8 af[4], bff[4];
#pragma unroll
      for (int mi = 0; mi < 4; ++mi)
        af[mi] = *(const bf16x8*)(As + (wr * 64 + mi * 16 + fr) * 64 + ko);
#pragma unroll
      for (int ni = 0; ni < 4; ++ni)
        bff[ni] = *(const bf16x8*)(Bs + (wc * 64 + ni * 16 + fr) * 64 + ko);
#pragma unroll
      for (int mi = 0; mi < 4; ++mi)
#pragma unroll
        for (int ni = 0; ni < 4; ++ni)
          acc[mi][ni] = __builtin_amdgcn_mfma_f32_16x16x32_bf16(af[mi], bff[ni], acc[mi][ni], 0, 0, 0);
    }
    __syncthreads();
  }

  const int fq = l >> 4;
#pragma unroll
  for (int ni = 0; ni < 4; ++ni) {
    const long col = bCol + wc * 64 + ni * 16 + fr;
    const float bs = bias ? bias[col] : 0.f;
#pragma unroll
    for (int mi = 0; mi < 4; ++mi) {
#pragma unroll
      for (int r = 0; r < 4; ++r) {
        const long row = bRow + wr * 64 + mi * 16 + fq * 4 + r;
        float v = acc[mi][ni][r] + bs;
        if (EPI == 1) v = 0.5f * v * (1.f + erff(v * 0.70710678118654752f));
        else if (EPI == 2) v = 1.f + 0.5f * tanhf(v);
        else if (EPI == 3) v = fmaxf(v, 0.f);
        else if (EPI == 5) v += bf2f(addend[row * N + col]);
        else if (EPI == 6) v = 0.5f * tanhf(v);
        if (EPI == 4) Cf[row * N + col] = v;
        else          Co[row * N + col] = f2bf(v);
      }
    }
  }
}

// ---------------- attention: per (batch, head), T=32, DH=128 ----------------
// o may alias q (blocks touch disjoint (b,h) slices; q reads precede o writes)
__global__ __launch_bounds__(64) void attn_kernel(const u16* q,
                                                  const u16* __restrict__ k,
                                                  const u16* __restrict__ v,
                                                  u16* o) {
  const int bh = blockIdx.x;
  const int b = bh >> 3, hd = bh & 7;
  const long base = (long)b * 32 * 1024 + hd * 128;
  const int l = threadIdx.x, lo = l & 31, hi = l >> 5;
  __shared__ u16 P[32 * 36];
  __shared__ u16 Vt[128 * 36];

  // stage V transposed: Vt[d][tok], stride 36
#pragma unroll
  for (int i = 0; i < 8; ++i) {
    int idx = i * 64 + l;
    int tok = idx >> 4, d0 = (idx & 15) * 8;
    const u16* src = v + base + (long)tok * 1024 + d0;
    ushort4 a0 = *(const ushort4*)src;
    ushort4 a1 = *(const ushort4*)(src + 4);
    u16 vals[8] = {a0.x, a0.y, a0.z, a0.w, a1.x, a1.y, a1.z, a1.w};
#pragma unroll
    for (int j = 0; j < 8; ++j) Vt[(d0 + j) * 36 + tok] = vals[j];
  }

  // S^T = K Q^T  (rows = k-token, cols = q-token)
  f32x16 st;
#pragma unroll
  for (int r = 0; r < 16; ++r) st[r] = 0.f;
#pragma unroll
  for (int kb = 0; kb < 8; ++kb) {
    bf16x8 kf = *(const bf16x8*)(k + base + (long)lo * 1024 + kb * 16 + hi * 8);
    bf16x8 qf = *(const bf16x8*)(q + base + (long)lo * 1024 + kb * 16 + hi * 8);
    st = __builtin_amdgcn_mfma_f32_32x32x16_bf16(kf, qf, st, 0, 0, 0);
  }
  float mx = -1e30f;
#pragma unroll
  for (int r = 0; r < 16; ++r) { st[r] *= 0.08838834764831845f; mx = fmaxf(mx, st[r]); }
  mx = fmaxf(mx, __shfl_xor(mx, 32));
  float p[16], sum = 0.f;
#pragma unroll
  for (int r = 0; r < 16; ++r) { p[r] = __expf(st[r] - mx); sum += p[r]; }
  sum += __shfl_xor(sum, 32);
  const float inv = 1.f / sum;
#pragma unroll
  for (int r = 0; r < 16; ++r) {
    int kt = (r & 3) + 8 * (r >> 2) + 4 * hi;
    P[lo * 36 + kt] = f2bf(p[r] * inv);
  }
  __syncthreads();

  // O = P @ V  (per 32-wide d block)
#pragma unroll
  for (int nb = 0; nb < 4; ++nb) {
    f32x16 oa;
#pragma unroll
    for (int r = 0; r < 16; ++r) oa[r] = 0.f;
#pragma unroll
    for (int ks = 0; ks < 2; ++ks) {
      union { bf16x8 v8; ushort4 h[2]; } pa, vb;
      pa.h[0] = *(const ushort4*)&P[lo * 36 + ks * 16 + hi * 8];
      pa.h[1] = *(const ushort4*)&P[lo * 36 + ks * 16 + hi * 8 + 4];
      vb.h[0] = *(const ushort4*)&Vt[(nb * 32 + lo) * 36 + ks * 16 + hi * 8];
      vb.h[1] = *(const ushort4*)&Vt[(nb * 32 + lo) * 36 + ks * 16 + hi * 8 + 4];
      oa = __builtin_amdgcn_mfma_f32_32x32x16_bf16(pa.v8, vb.v8, oa, 0, 0, 0);
    }
#pragma unroll
    for (int r = 0; r < 16; ++r) {
      int qrow = (r & 3) + 8 * (r >> 2) + 4 * hi;
      o[base + (long)qrow * 1024 + nb * 32 + lo] = f2bf(oa[r]);
    }
  }
}

// ---------------- launch ----------------
extern "C" void kernel_launch(void* const* d_in, const int* in_sizes, int n_in,
                              void* d_out, int out_size, void* d_ws, size_t ws_size,
                              hipStream_t stream) {
  const float* state = (const float*)d_in[0];  const float* cond  = (const float*)d_in[1];
  const float* ew1 = (const float*)d_in[2];    const float* eb1 = (const float*)d_in[3];
  const float* eg1 = (const float*)d_in[4];    const float* ebt1 = (const float*)d_in[5];
  const float* ew2 = (const float*)d_in[6];    const float* eb2 = (const float*)d_in[7];
  const float* eg2 = (const float*)d_in[8];    const float* ebt2 = (const float*)d_in[9];
  const float* rw = (const float*)d_in[10];    const float* rb = (const float*)d_in[11];
  const float* fw1 = (const float*)d_in[12];   const float* fb1 = (const float*)d_in[13];
  const float* fw2 = (const float*)d_in[14];   const float* fb2 = (const float*)d_in[15];
  const float* lnq_g = (const float*)d_in[16]; const float* lnq_b = (const float*)d_in[17];
  const float* wq = (const float*)d_in[18];    const float* wk = (const float*)d_in[19];
  const float* wv = (const float*)d_in[20];    const float* wo = (const float*)d_in[21];
  const float* cn_g = (const float*)d_in[22];  const float* cn_b = (const float*)d_in[23];
  const float* hw1 = (const float*)d_in[24];   const float* hb1 = (const float*)d_in[25];
  const float* hw2 = (const float*)d_in[26];   const float* hb2 = (const float*)d_in[27];

  const size_t MB128 = 134217728ULL;
  const size_t WT_BYTES = 17367040ULL;  // 8683520 u16 elems
  char* ws = (char*)d_ws;
  u16* OUTu = (u16*)d_out;
  float* OUTf = (float*)d_out;

  // decide plan + weight-region location
  u16* wt = nullptr;
  bool planA = false;
  int R = 0;
  if (ws_size >= 4 * MB128 + 16777216ULL + WT_BYTES) {           // 571,015,168
    planA = true;
    wt = (u16*)(ws + 4 * MB128 + 16777216ULL);
  } else {
    for (int r = 8192; r >= 1024; r >>= 1) {
      size_t need = 2 * MB128 + (size_t)r * 8448ULL + WT_BYTES;
      if (ws_size >= need) { R = r; wt = (u16*)(ws + 2 * MB128 + (size_t)r * 8448ULL); break; }
    }
    if (!R) return;  // workspace too small for any plan
  }

  u16* ew1T = wt + 0;        u16* rwT  = wt + 786432;  u16* ew2T = wt + 1572864;
  u16* fw1T = wt + 2621440;  u16* fw2T = wt + 2654208;
  u16* wqT  = wt + 2916352;  u16* wkT  = wt + 3964928; u16* wvT  = wt + 5013504;
  u16* woT  = wt + 6062080;  u16* hw1T = wt + 7110656; u16* hw2T = wt + 8159232;

  // weight transposes (fp32 [K][N] -> bf16 [N][K])
  transpose_cvt<<<dim3(32, 24), 256, 0, stream>>>(ew1, ew1T, 768, 1024);
  transpose_cvt<<<dim3(32, 24), 256, 0, stream>>>(rw,  rwT,  768, 1024);
  transpose_cvt<<<dim3(32, 32), 256, 0, stream>>>(ew2, ew2T, 1024, 1024);
  transpose_cvt<<<dim3(4, 8),   256, 0, stream>>>(fw1, fw1T, 256, 128);
  transpose_cvt<<<dim3(64, 4),  256, 0, stream>>>(fw2, fw2T, 128, 2048);
  transpose_cvt<<<dim3(32, 32), 256, 0, stream>>>(wq, wqT, 1024, 1024);
  transpose_cvt<<<dim3(32, 32), 256, 0, stream>>>(wk, wkT, 1024, 1024);
  transpose_cvt<<<dim3(32, 32), 256, 0, stream>>>(wv, wvT, 1024, 1024);
  transpose_cvt<<<dim3(32, 32), 256, 0, stream>>>(wo, woT, 1024, 1024);
  transpose_cvt<<<dim3(32, 32), 256, 0, stream>>>(hw1, hw1T, 1024, 1024);
  transpose_cvt<<<dim3(16, 32), 256, 0, stream>>>(hw2, hw2T, 1024, 512);

  if (planA) {
    u16* W1 = (u16*)ws;
    u16* W2 = (u16*)(ws + MB128);
    u16* W3 = (u16*)(ws + 2 * MB128);
    u16* W4 = (u16*)(ws + 3 * MB128);
    u16* fh = (u16*)(ws + 4 * MB128);

    prep_kernel<<<49152, 256, 0, stream>>>(state, cond, W1);                               // xb=W1
    gemm_bt<1><<<dim3(512, 1), 256, 0, stream>>>(W1 + 512, fw1T, fb1, nullptr, fh, nullptr, 128, 256, 768);
    gemm_bt<0><<<dim3(512, 8), 256, 0, stream>>>(W1, ew1T, eb1, nullptr, W2, nullptr, 1024, 768, 768);   // y1=W2
    gemm_bt<0><<<dim3(512, 8), 256, 0, stream>>>(W1, rwT,  rb,  nullptr, W3, nullptr, 1024, 768, 768);   // res=W3
    ln_relu_kernel<<<65536, 256, 0, stream>>>(W2, eg1, ebt1, W1);                          // h1=W1 (xb dead)
    gemm_bt<0><<<dim3(512, 8), 256, 0, stream>>>(W1, ew2T, eb2, nullptr, W2, nullptr, 1024, 1024, 1024); // y2=W2
    ln_relu_kernel<<<65536, 256, 0, stream>>>(W2, eg2, ebt2, W4);                          // hbf=W4
    gemm_bt<2><<<dim3(512, 8), 256, 0, stream>>>(fh, fw2T, fb2, nullptr, W2, nullptr, 1024, 128, 128);        // gain=W2
    gemm_bt<6><<<dim3(512, 8), 256, 0, stream>>>(fh, fw2T + 131072, fb2 + 1024, nullptr, W1, nullptr, 1024, 128, 128); // bias=W1
    qin_kernel<<<65536, 256, 0, stream>>>(W4, W2, W1, lnq_g, lnq_b, OUTu);                 // qin=OUT
    gemm_bt<0><<<dim3(512, 8), 256, 0, stream>>>(OUTu, wqT, nullptr, nullptr, W2, nullptr, 1024, 1024, 1024); // q=W2
    gemm_bt<0><<<dim3(512, 8), 256, 0, stream>>>(W4, wkT, nullptr, nullptr, W1, nullptr, 1024, 1024, 1024);   // k=W1
    gemm_bt<0><<<dim3(512, 8), 256, 0, stream>>>(W4, wvT, nullptr, nullptr, OUTu, nullptr, 1024, 1024, 1024); // v=OUT
    attn_kernel<<<16384, 64, 0, stream>>>(W2, W1, OUTu, W2);                               // o=W2 (in-place over q)
    gemm_bt<5><<<dim3(512, 8), 256, 0, stream>>>(W2, woT, nullptr, W3, W3, nullptr, 1024, 1024, 1024);   // o2=W3 (+res, in-place)
    h2_kernel<<<65536, 256, 0, stream>>>(W4, W3, cn_g, cn_b, W1);                          // h2=W1
    gemm_bt<3><<<dim3(512, 8), 256, 0, stream>>>(W1, hw1T, hb1, nullptr, W2, nullptr, 1024, 1024, 1024); // mh=W2
    gemm_bt<4><<<dim3(512, 4), 256, 0, stream>>>(W2, hw2T, hb2, nullptr, nullptr, OUTf, 512, 1024, 1024);
    return;
  }

  // ---- Plan C: chunked over rows, R rows per chunk ----
  u16* F1 = (u16*)ws;              // hbf (full)
  u16* F2 = (u16*)(ws + MB128);    // res -> o2 (full)
  char* g = ws + 2 * MB128;
  u16* G0 = (u16*)g;                                   // xb / y2 / q / o
  u16* G1 = (u16*)(g + (size_t)R * 2048);              // y1 / bias / k
  u16* G2 = (u16*)(g + (size_t)R * 4096);              // fh
  u16* G3 = (u16*)(g + (size_t)R * 4096 + (size_t)R * 256); // h1 / gain / qin
  u16* G4 = (u16*)(g + (size_t)R * 6144 + (size_t)R * 256); // v
  const int GX = R / 128, CH = 65536 / R;

  for (int c = 0; c < CH; ++c) {
    const long r0 = (long)c * R;
    prep_kernel<<<R * 3 / 4, 256, 0, stream>>>(state + r0 * 512, cond + r0 * 256, G0);
    gemm_bt<1><<<dim3(GX, 1), 256, 0, stream>>>(G0 + 512, fw1T, fb1, nullptr, G2, nullptr, 128, 256, 768);
    gemm_bt<0><<<dim3(GX, 8), 256, 0, stream>>>(G0, ew1T, eb1, nullptr, G1, nullptr, 1024, 768, 768);
    gemm_bt<0><<<dim3(GX, 8), 256, 0, stream>>>(G0, rwT,  rb,  nullptr, F2 + r0 * 1024, nullptr, 1024, 768, 768);
    ln_relu_kernel<<<R, 256, 0, stream>>>(G1, eg1, ebt1, G3);
    gemm_bt<0><<<dim3(GX, 8), 256, 0, stream>>>(G3, ew2T, eb2, nullptr, G0, nullptr, 1024, 1024, 1024);
    ln_relu_kernel<<<R, 256, 0, stream>>>(G0, eg2, ebt2, F1 + r0 * 1024);
    gemm_bt<2><<<dim3(GX, 8), 256, 0, stream>>>(G2, fw2T, fb2, nullptr, G3, nullptr, 1024, 128, 128);
    gemm_bt<6><<<dim3(GX, 8), 256, 0, stream>>>(G2, fw2T + 131072, fb2 + 1024, nullptr, G1, nullptr, 1024, 128, 128);
    qin_kernel<<<R, 256, 0, stream>>>(F1 + r0 * 1024, G3, G1, lnq_g, lnq_b, G3);  // in-place over gain
    gemm_bt<0><<<dim3(GX, 8), 256, 0, stream>>>(G3, wqT, nullptr, nullptr, G0, nullptr, 1024, 1024, 1024);
    gemm_bt<0><<<dim3(GX, 8), 256, 0, stream>>>(F1 + r0 * 1024, wkT, nullptr, nullptr, G1, nullptr, 1024, 1024, 1024);
    gemm_bt<0><<<dim3(GX, 8), 256, 0, stream>>>(F1 + r0 * 1024, wvT, nullptr, nullptr, G4, nullptr, 1024, 1024, 1024);
    attn_kernel<<<(R / 32) * 8, 64, 0, stream>>>(G0, G1, G4, G0);                 // in-place over q
    gemm_bt<5><<<dim3(GX, 8), 256, 0, stream>>>(G0, woT, nullptr, F2 + r0 * 1024, F2 + r0 * 1024, nullptr, 1024, 1024, 1024);
  }
  h2_kernel<<<65536, 256, 0, stream>>>(F1, F2, cn_g, cn_b, OUTu);                 // h2 -> OUT (scratch)
  gemm_bt<3><<<dim3(512, 8), 256, 0, stream>>>(OUTu, hw1T, hb1, nullptr, F1, nullptr, 1024, 1024, 1024);
  gemm_bt<4><<<dim3(512, 4), 256, 0, stream>>>(F1, hw2T, hb2, nullptr, nullptr, OUTf, 512, 1024, 1024);
}

// Round 3
// 3375.033 us; speedup vs baseline: 1.0241x; 1.0241x over previous
//
#include <hip/hip_runtime.h>
#include <hip/hip_bf16.h>

typedef unsigned short u16;
typedef short bf16x8 __attribute__((ext_vector_type(8)));
typedef float f32x4 __attribute__((ext_vector_type(4)));
typedef float f32x16 __attribute__((ext_vector_type(16)));

#define DEV __device__ __forceinline__

DEV u16 f2bf(float f) {
  union { float f; unsigned u; } a; a.f = f;
  unsigned r = a.u + 0x7FFFu + ((a.u >> 16) & 1u);
  return (u16)(r >> 16);
}
DEV float bf2f(u16 u) {
  union { unsigned u; float f; } a; a.u = ((unsigned)u) << 16; return a.f;
}
DEV void async16(const void* g, void* l) {
  __builtin_amdgcn_global_load_lds(
      (const __attribute__((address_space(1))) unsigned int*)g,
      (__attribute__((address_space(3))) unsigned int*)l, 16, 0, 0);
}

#define SBAR() asm volatile("s_barrier" ::: "memory")

// ---------------- transpose + cvt: in fp32 [K][N] -> out bf16 [N][K] ----------------
__global__ __launch_bounds__(256) void transpose_cvt(const float* __restrict__ in,
                                                     u16* __restrict__ out, int K, int N) {
  __shared__ float tile[32][33];
  const int kt = blockIdx.y * 32, nt = blockIdx.x * 32;
  const int tx = threadIdx.x & 31, ty = threadIdx.x >> 5;
#pragma unroll
  for (int i = 0; i < 32; i += 8) {
    int k = kt + ty + i, n = nt + tx;
    tile[ty + i][tx] = (k < K && n < N) ? in[(long)k * N + n] : 0.f;
  }
  __syncthreads();
#pragma unroll
  for (int i = 0; i < 32; i += 8) {
    int n = nt + ty + i, k = kt + tx;
    if (n < N && k < K) out[(long)n * K + k] = f2bf(tile[tx][ty + i]);
  }
}

// ---------------- prep: concat + clip -> bf16 x [R][768] ----------------
__global__ __launch_bounds__(256) void prep_kernel(const float* __restrict__ state,
                                                   const float* __restrict__ cond,
                                                   u16* __restrict__ xb) {
  int idx = blockIdx.x * 256 + threadIdx.x;
  int t = idx / 192, c4 = idx - t * 192;
  float4 v;
  if (c4 < 128) v = ((const float4*)state)[(long)t * 128 + c4];
  else          v = ((const float4*)cond)[(long)t * 64 + (c4 - 128)];
  ushort4 o;
  o.x = f2bf(fminf(fmaxf(v.x, -16.f), 16.f));
  o.y = f2bf(fminf(fmaxf(v.y, -16.f), 16.f));
  o.z = f2bf(fminf(fmaxf(v.z, -16.f), 16.f));
  o.w = f2bf(fminf(fmaxf(v.w, -16.f), 16.f));
  *(ushort4*)(xb + (long)t * 768 + c4 * 4) = o;
}

// ---------------- block reduction (256 threads, 4 waves) ----------------
DEV void reduce2(float& s, float& q, float* sh, int tid) {
#pragma unroll
  for (int off = 32; off; off >>= 1) { s += __shfl_xor(s, off); q += __shfl_xor(q, off); }
  const int w = tid >> 6;
  if ((tid & 63) == 0) { sh[w] = s; sh[4 + w] = q; }
  __syncthreads();
  s = sh[0] + sh[1] + sh[2] + sh[3];
  q = sh[4] + sh[5] + sh[6] + sh[7];
}

// ---------------- LN (+ReLU) rowwise, H=1024 ----------------
__global__ __launch_bounds__(256) void ln_relu_kernel(const u16* __restrict__ in,
                                                      const float* __restrict__ g,
                                                      const float* __restrict__ bt,
                                                      u16* __restrict__ out) {
  __shared__ float sh[8];
  const long row = blockIdx.x;
  const int tid = threadIdx.x;
  ushort4 hv = *(const ushort4*)(in + row * 1024 + tid * 4);
  float x[4] = {bf2f(hv.x), bf2f(hv.y), bf2f(hv.z), bf2f(hv.w)};
  float s = x[0] + x[1] + x[2] + x[3];
  float q = x[0]*x[0] + x[1]*x[1] + x[2]*x[2] + x[3]*x[3];
  reduce2(s, q, sh, tid);
  float mean = s * (1.f / 1024.f);
  float var  = q * (1.f / 1024.f) - mean * mean;
  float rs   = rsqrtf(var + 1e-5f);
  ushort4 ov; u16* op = (u16*)&ov;
#pragma unroll
  for (int j = 0; j < 4; ++j) {
    int c = tid * 4 + j;
    float y = (x[j] - mean) * rs * g[c] + bt[c];
    op[j] = f2bf(fmaxf(y, 0.f));
  }
  *(ushort4*)(out + row * 1024 + tid * 4) = ov;
}

// ---------------- qin = LN(h)*gain + bias; gb interleaved [row][2048] ----------------
__global__ __launch_bounds__(256) void qin_kernel(const u16* __restrict__ h,
                                                  const u16* gb,
                                                  const float* __restrict__ lg,
                                                  const float* __restrict__ lbt,
                                                  u16* qout) {
  __shared__ float sh[8];
  const long row = blockIdx.x;
  const int tid = threadIdx.x;
  ushort4 hv = *(const ushort4*)(h + row * 1024 + tid * 4);
  float x[4] = {bf2f(hv.x), bf2f(hv.y), bf2f(hv.z), bf2f(hv.w)};
  float s = x[0] + x[1] + x[2] + x[3];
  float q = x[0]*x[0] + x[1]*x[1] + x[2]*x[2] + x[3]*x[3];
  reduce2(s, q, sh, tid);
  float mean = s * (1.f / 1024.f);
  float var  = q * (1.f / 1024.f) - mean * mean;
  float rs   = rsqrtf(var + 1e-5f);
  ushort4 gv = *(const ushort4*)(gb + row * 2048 + tid * 4);
  ushort4 bv = *(const ushort4*)(gb + row * 2048 + 1024 + tid * 4);
  const u16* gp = (const u16*)&gv;
  const u16* bp = (const u16*)&bv;
  ushort4 ov; u16* op = (u16*)&ov;
#pragma unroll
  for (int j = 0; j < 4; ++j) {
    int c = tid * 4 + j;
    float y = (x[j] - mean) * rs * lg[c] + lbt[c];
    op[j] = f2bf(y * bf2f(gp[j]) + bf2f(bp[j]));
  }
  *(ushort4*)(qout + row * 1024 + tid * 4) = ov;
}

// ---------------- h2 = LN(h + o2) ----------------
__global__ __launch_bounds__(256) void h2_kernel(const u16* __restrict__ h,
                                                 const u16* o2,
                                                 const float* __restrict__ g,
                                                 const float* __restrict__ bt,
                                                 u16* out) {
  __shared__ float sh[8];
  const long row = blockIdx.x;
  const int tid = threadIdx.x;
  ushort4 a = *(const ushort4*)(h  + row * 1024 + tid * 4);
  ushort4 b = *(const ushort4*)(o2 + row * 1024 + tid * 4);
  const u16* ap = (const u16*)&a; const u16* bp = (const u16*)&b;
  float x[4];
#pragma unroll
  for (int j = 0; j < 4; ++j) x[j] = bf2f(ap[j]) + bf2f(bp[j]);
  float s = x[0] + x[1] + x[2] + x[3];
  float q = x[0]*x[0] + x[1]*x[1] + x[2]*x[2] + x[3]*x[3];
  reduce2(s, q, sh, tid);
  float mean = s * (1.f / 1024.f);
  float var  = q * (1.f / 1024.f) - mean * mean;
  float rs   = rsqrtf(var + 1e-5f);
  ushort4 ov; u16* op = (u16*)&ov;
#pragma unroll
  for (int j = 0; j < 4; ++j) {
    int c = tid * 4 + j;
    op[j] = f2bf((x[j] - mean) * rs * g[c] + bt[c]);
  }
  *(ushort4*)(out + row * 1024 + tid * 4) = ov;
}

// ============ old 128x128 GEMM (FiLM1 + Plan C fallback) ============
// EPI: 0=bias->bf16, 1=gelu->bf16, 2=1+0.5tanh->bf16, 3=relu->bf16, 4=bias->f32,
//      5=+addend->bf16, 6=0.5tanh->bf16
template <int EPI>
__global__ __launch_bounds__(256) void gemm_bt(const u16* __restrict__ A,
                                               const u16* __restrict__ Bt,
                                               const float* __restrict__ bias,
                                               const u16* addend,
                                               u16* Co, float* Cf,
                                               int N, int K, int lda) {
  __shared__ u16 As[128 * 64];
  __shared__ u16 Bs[128 * 64];
  const int tid = threadIdx.x;
  const int w = tid >> 6, l = tid & 63;
  const int wr = w >> 1, wc = w & 1;
  const long bRow = (long)blockIdx.x * 128;
  const long bCol = (long)blockIdx.y * 128;

  f32x4 acc[4][4];
#pragma unroll
  for (int mi = 0; mi < 4; ++mi)
#pragma unroll
    for (int ni = 0; ni < 4; ++ni) acc[mi][ni] = (f32x4){0.f, 0.f, 0.f, 0.f};

  const int arow = l >> 3;
  const int acol = (l & 7) * 8;
  const u16* gA = A + (bRow + w * 8 + arow) * (long)lda + acol;
  const u16* gB = Bt + (bCol + w * 8 + arow) * (long)K + acol;

  const int fr = l & 15;
  const int fks = (l >> 4) * 8;

  for (int kt = 0; kt < K; kt += 64) {
#pragma unroll
    for (int i = 0; i < 4; ++i) {
      async16(gA + (long)i * 32 * lda + kt, As + (i * 32 + w * 8) * 64);
      async16(gB + (long)i * 32 * K   + kt, Bs + (i * 32 + w * 8) * 64);
    }
    __syncthreads();
#pragma unroll
    for (int kk = 0; kk < 2; ++kk) {
      const int ko = kk * 32 + fks;
      bf16x8 af[4], bff[4];
#pragma unroll
      for (int mi = 0; mi < 4; ++mi)
        af[mi] = *(const bf16x8*)(As + (wr * 64 + mi * 16 + fr) * 64 + ko);
#pragma unroll
      for (int ni = 0; ni < 4; ++ni)
        bff[ni] = *(const bf16x8*)(Bs + (wc * 64 + ni * 16 + fr) * 64 + ko);
#pragma unroll
      for (int mi = 0; mi < 4; ++mi)
#pragma unroll
        for (int ni = 0; ni < 4; ++ni)
          acc[mi][ni] = __builtin_amdgcn_mfma_f32_16x16x32_bf16(af[mi], bff[ni], acc[mi][ni], 0, 0, 0);
    }
    __syncthreads();
  }

  const int fq = l >> 4;
#pragma unroll
  for (int ni = 0; ni < 4; ++ni) {
    const long col = bCol + wc * 64 + ni * 16 + fr;
    const float bs = bias ? bias[col] : 0.f;
#pragma unroll
    for (int mi = 0; mi < 4; ++mi) {
#pragma unroll
      for (int r = 0; r < 4; ++r) {
        const long row = bRow + wr * 64 + mi * 16 + fq * 4 + r;
        float v = acc[mi][ni][r] + bs;
        if (EPI == 1) v = 0.5f * v * (1.f + erff(v * 0.70710678118654752f));
        else if (EPI == 2) v = 1.f + 0.5f * tanhf(v);
        else if (EPI == 3) v = fmaxf(v, 0.f);
        else if (EPI == 5) v += bf2f(addend[row * N + col]);
        else if (EPI == 6) v = 0.5f * tanhf(v);
        if (EPI == 4) Cf[row * N + col] = v;
        else          Co[row * N + col] = f2bf(v);
      }
    }
  }
}

// ============ 256x256 / BK=64 / 8-phase pipelined GEMM ============
// EPI: 0=bias->bf16, 2=FiLM(col<1024?1+.5tanh:.5tanh)->bf16, 3=relu->bf16,
//      4=bias->f32, 5=+addend->bf16 (alias ok), 6=kv-split (Co=k, Co2=v)
// LDS 128 KiB dynamic: A0|A1 @ [0,64K), B0|B1 @ [64K,128K). st_16x32 swizzle:
// linear LDS dest (global_load_lds), pre-swizzled global source, swizzled ds_read.
#define RDA(buf, Qr) do { \
  _Pragma("unroll") for (int ks_ = 0; ks_ < 2; ++ks_) \
  _Pragma("unroll") for (int m_ = 0; m_ < 4; ++m_) \
    a[ks_][m_] = *(const bf16x8*)(ldsc + (buf) * 32768 + \
      ((Qr) * 128 + wr * 64 + m_ * 16 + fr) * 128 + ((ks_ * 64 + fq * 16) ^ swzc)); \
} while (0)

#define RDB(buf, Qc, bb) do { \
  _Pragma("unroll") for (int ks_ = 0; ks_ < 2; ++ks_) \
  _Pragma("unroll") for (int n_ = 0; n_ < 2; ++n_) \
    bb[ks_][n_] = *(const bf16x8*)(ldsc + 65536 + (buf) * 32768 + \
      ((Qc) * 128 + wc * 32 + n_ * 16 + fr) * 128 + ((ks_ * 64 + fq * 16) ^ swzc)); \
} while (0)

#define MM(Qr, Qc, bb) do { \
  __builtin_amdgcn_s_setprio(1); \
  _Pragma("unroll") for (int m_ = 0; m_ < 4; ++m_) \
  _Pragma("unroll") for (int n_ = 0; n_ < 2; ++n_) \
  _Pragma("unroll") for (int ks_ = 0; ks_ < 2; ++ks_) \
    acc[Qr][Qc][m_][n_] = __builtin_amdgcn_mfma_f32_16x16x32_bf16( \
        a[ks_][m_], bb[ks_][n_], acc[Qr][Qc][m_][n_], 0, 0, 0); \
  __builtin_amdgcn_s_setprio(0); \
} while (0)

#define STA(buf, tt, h) do { \
  _Pragma("unroll") for (int j_ = 0; j_ < 2; ++j_) \
    async16(aBase0 + j_ * 8192 * (long)lda_l + (h) * 128 * (long)lda_l + (tt) * 64, \
            ldsc + (buf) * 32768 + (h) * 16384 + (j_ * 512 + tid) * 16); \
} while (0)

#define STB(buf, tt, h) do { \
  _Pragma("unroll") for (int j_ = 0; j_ < 2; ++j_) \
    async16(bBase0 + j_ * 8192 * (long)K_l + (h) * 128 * (long)K_l + (tt) * 64, \
            ldsc + 65536 + (buf) * 32768 + (h) * 16384 + (j_ * 512 + tid) * 16); \
} while (0)

template <int EPI>
__global__ __launch_bounds__(512, 1) void gemm256(const u16* __restrict__ A,
                                                  const u16* __restrict__ Bt,
                                                  const float* __restrict__ bias,
                                                  const u16* addend,
                                                  u16* Co, u16* Co2, float* Cf,
                                                  int N, int K, int lda, int ctLog) {
  extern __shared__ char ldsc[];
  const int tid = threadIdx.x;
  const int l = tid & 63;
  const int w = tid >> 6, wr = w >> 2, wc = w & 3;
  const int fr = l & 15, fq = l >> 4;
  const int swzc = (fr & 7) << 4;
  const int lda_l = lda, K_l = K;

  // XCD-chunked bijective swizzle (nwg % 8 == 0 for all our shapes)
  const int nwg = gridDim.x;
  const int orig = blockIdx.x;
  const int swz = (orig & 7) * (nwg >> 3) + (orig >> 3);
  const int rt = swz >> ctLog, ct = swz & ((1 << ctLog) - 1);
  const long bRow = (long)rt * 256, bCol = (long)ct * 256;

  const int NT = K >> 6;  // even, >= 2

  // per-thread stage base for chunk j=0; chunk row = (j*512+tid)*16B >> 7
  {
  }
  const int L0 = tid * 16;
  const int row0 = L0 >> 7;                       // 0..15
  const int colb0 = (L0 & 127) ^ ((row0 & 7) << 4);
  const u16* aBase0 = A + (bRow + row0) * (long)lda + (colb0 >> 1);
  const u16* bBase0 = Bt + (bCol + row0) * (long)K + (colb0 >> 1);
  // chunk j=1 is rows +64? No: (512*16)>>7 = 64 rows further -> j_*8192*lda elems? 
  // (j*512+tid)*16 bytes = L0 + j*8192 bytes -> row += 64 -> offset j*64*lda elems.
  // NOTE: 8192 bytes / 128 B-per-row = 64 rows; expressed below as j_*8192*(lda)/... 
  // We fold it as j_*64 rows: j_*8192*(long)lda_l/128 == j_*64*lda_l.
  // (STA macro uses j_*8192*(long)lda_l; fix factor here by pre-dividing.)

  f32x4 acc[2][2][4][2];
#pragma unroll
  for (int p = 0; p < 2; ++p)
#pragma unroll
    for (int qq = 0; qq < 2; ++qq)
#pragma unroll
      for (int m = 0; m < 4; ++m)
#pragma unroll
        for (int n = 0; n < 2; ++n) acc[p][qq][m][n] = (f32x4){0.f, 0.f, 0.f, 0.f};

  bf16x8 a[2][4], b0[2][2], b1[2][2];

  // prologue: tile0 all 4 halves, tile1 A-h0 + B-h1
  {
#pragma unroll
    for (int j_ = 0; j_ < 2; ++j_) {
      async16(aBase0 + j_ * 64 * (long)lda_l, ldsc + (j_ * 512 + tid) * 16);
      async16(aBase0 + j_ * 64 * (long)lda_l + 128 * (long)lda_l, ldsc + 16384 + (j_ * 512 + tid) * 16);
      async16(bBase0 + j_ * 64 * (long)K_l, ldsc + 65536 + (j_ * 512 + tid) * 16);
      async16(bBase0 + j_ * 64 * (long)K_l + 128 * (long)K_l, ldsc + 65536 + 16384 + (j_ * 512 + tid) * 16);
    }
    if (NT > 1) {
#pragma unroll
      for (int j_ = 0; j_ < 2; ++j_) {
        async16(aBase0 + j_ * 64 * (long)lda_l + 64, ldsc + 32768 + (j_ * 512 + tid) * 16);
        async16(bBase0 + j_ * 64 * (long)K_l + 128 * (long)K_l + 64, ldsc + 65536 + 32768 + 16384 + (j_ * 512 + tid) * 16);
      }
    }
  }
  asm volatile("s_waitcnt vmcnt(4)" ::: "memory");
  SBAR();

#undef STA
#undef STB
#define STA(buf, tt, h) do { \
  _Pragma("unroll") for (int j_ = 0; j_ < 2; ++j_) \
    async16(aBase0 + (j_ * 64 + (h) * 128) * (long)lda_l + (tt) * 64, \
            ldsc + (buf) * 32768 + (h) * 16384 + (j_ * 512 + tid) * 16); \
} while (0)
#define STB(buf, tt, h) do { \
  _Pragma("unroll") for (int j_ = 0; j_ < 2; ++j_) \
    async16(bBase0 + (j_ * 64 + (h) * 128) * (long)K_l + (tt) * 64, \
            ldsc + 65536 + (buf) * 32768 + (h) * 16384 + (j_ * 512 + tid) * 16); \
} while (0)

  for (int i = 0; i < (NT >> 1); ++i) {
    const int t0 = i * 2, t1 = t0 + 1;
    const bool more = (t0 + 2) < NT;
    // ph1: q(0,0) of t0 (buf0)
    RDA(0, 0); RDB(0, 0, b0);
    STA(1, t1, 1);
    SBAR(); MM(0, 0, b0); SBAR();
    // ph2: q(0,1)
    RDB(0, 1, b1);
    STB(1, t1, 0);
    SBAR(); MM(0, 1, b1); SBAR();
    // ph3: q(1,1)
    RDA(0, 1);
    if (more) STA(0, t0 + 2, 0);
    SBAR(); MM(1, 1, b1); SBAR();
    // ph4: q(1,0)
    if (more) STB(0, t0 + 2, 1);
    SBAR(); MM(1, 0, b0);
    if (more) asm volatile("s_waitcnt vmcnt(4)" ::: "memory");
    else      asm volatile("s_waitcnt vmcnt(0)" ::: "memory");
    SBAR();
    // ph5: q(0,0) of t1 (buf1)
    RDA(1, 0); RDB(1, 0, b0);
    if (more) STA(0, t0 + 2, 1);
    SBAR(); MM(0, 0, b0); SBAR();
    // ph6: q(0,1)
    RDB(1, 1, b1);
    if (more) STB(0, t0 + 2, 0);
    SBAR(); MM(0, 1, b1); SBAR();
    // ph7: q(1,1)
    RDA(1, 1);
    if (more) STA(1, t1 + 2, 0);
    SBAR(); MM(1, 1, b1); SBAR();
    // ph8: q(1,0)
    if (more) STB(1, t1 + 2, 1);
    SBAR(); MM(1, 0, b0);
    if (more) asm volatile("s_waitcnt vmcnt(4)" ::: "memory");
    else      asm volatile("s_waitcnt vmcnt(0)" ::: "memory");
    SBAR();
  }

  // epilogue
#pragma unroll
  for (int Qr = 0; Qr < 2; ++Qr)
#pragma unroll
    for (int Qc = 0; Qc < 2; ++Qc)
#pragma unroll
      for (int n = 0; n < 2; ++n) {
        const long col = bCol + Qc * 128 + wc * 32 + n * 16 + fr;
        const float bs = bias ? bias[col] : 0.f;
#pragma unroll
        for (int m = 0; m < 4; ++m) {
#pragma unroll
          for (int r = 0; r < 4; ++r) {
            const long row = bRow + Qr * 128 + wr * 64 + m * 16 + fq * 4 + r;
            float v = acc[Qr][Qc][m][n][r] + bs;
            if (EPI == 2)      v = (col < 1024) ? 1.f + 0.5f * tanhf(v) : 0.5f * tanhf(v);
            else if (EPI == 3) v = fmaxf(v, 0.f);
            else if (EPI == 5) v += bf2f(addend[row * (long)N + col]);
            if (EPI == 4)      Cf[row * (long)N + col] = v;
            else if (EPI == 6) {
              if (col < 1024) Co[row * 1024 + col] = f2bf(v);
              else            Co2[row * 1024 + (col - 1024)] = f2bf(v);
            } else             Co[row * (long)N + col] = f2bf(v);
          }
        }
      }
}

// ---------------- attention: per (batch, head), T=32, DH=128 ----------------
__global__ __launch_bounds__(64) void attn_kernel(const u16* q,
                                                  const u16* __restrict__ k,
                                                  const u16* __restrict__ v,
                                                  u16* o) {
  const int bh = blockIdx.x;
  const int b = bh >> 3, hd = bh & 7;
  const long base = (long)b * 32 * 1024 + hd * 128;
  const int l = threadIdx.x, lo = l & 31, hi = l >> 5;
  __shared__ u16 P[32 * 36];
  __shared__ u16 Vt[128 * 36];

#pragma unroll
  for (int i = 0; i < 8; ++i) {
    int idx = i * 64 + l;
    int tok = idx >> 4, d0 = (idx & 15) * 8;
    const u16* src = v + base + (long)tok * 1024 + d0;
    ushort4 a0 = *(const ushort4*)src;
    ushort4 a1 = *(const ushort4*)(src + 4);
    u16 vals[8] = {a0.x, a0.y, a0.z, a0.w, a1.x, a1.y, a1.z, a1.w};
#pragma unroll
    for (int j = 0; j < 8; ++j) Vt[(d0 + j) * 36 + tok] = vals[j];
  }

  f32x16 st;
#pragma unroll
  for (int r = 0; r < 16; ++r) st[r] = 0.f;
#pragma unroll
  for (int kb = 0; kb < 8; ++kb) {
    bf16x8 kf = *(const bf16x8*)(k + base + (long)lo * 1024 + kb * 16 + hi * 8);
    bf16x8 qf = *(const bf16x8*)(q + base + (long)lo * 1024 + kb * 16 + hi * 8);
    st = __builtin_amdgcn_mfma_f32_32x32x16_bf16(kf, qf, st, 0, 0, 0);
  }
  float mx = -1e30f;
#pragma unroll
  for (int r = 0; r < 16; ++r) { st[r] *= 0.08838834764831845f; mx = fmaxf(mx, st[r]); }
  mx = fmaxf(mx, __shfl_xor(mx, 32));
  float p[16], sum = 0.f;
#pragma unroll
  for (int r = 0; r < 16; ++r) { p[r] = __expf(st[r] - mx); sum += p[r]; }
  sum += __shfl_xor(sum, 32);
  const float inv = 1.f / sum;
#pragma unroll
  for (int r = 0; r < 16; ++r) {
    int kt = (r & 3) + 8 * (r >> 2) + 4 * hi;
    P[lo * 36 + kt] = f2bf(p[r] * inv);
  }
  __syncthreads();

#pragma unroll
  for (int nb = 0; nb < 4; ++nb) {
    f32x16 oa;
#pragma unroll
    for (int r = 0; r < 16; ++r) oa[r] = 0.f;
#pragma unroll
    for (int ks = 0; ks < 2; ++ks) {
      union { bf16x8 v8; ushort4 h[2]; } pa, vb;
      pa.h[0] = *(const ushort4*)&P[lo * 36 + ks * 16 + hi * 8];
      pa.h[1] = *(const ushort4*)&P[lo * 36 + ks * 16 + hi * 8 + 4];
      vb.h[0] = *(const ushort4*)&Vt[(nb * 32 + lo) * 36 + ks * 16 + hi * 8];
      vb.h[1] = *(const ushort4*)&Vt[(nb * 32 + lo) * 36 + ks * 16 + hi * 8 + 4];
      oa = __builtin_amdgcn_mfma_f32_32x32x16_bf16(pa.v8, vb.v8, oa, 0, 0, 0);
    }
#pragma unroll
    for (int r = 0; r < 16; ++r) {
      int qrow = (r & 3) + 8 * (r >> 2) + 4 * hi;
      o[base + (long)qrow * 1024 + nb * 32 + lo] = f2bf(oa[r]);
    }
  }
}

// ---------------- launch ----------------
extern "C" void kernel_launch(void* const* d_in, const int* in_sizes, int n_in,
                              void* d_out, int out_size, void* d_ws, size_t ws_size,
                              hipStream_t stream) {
  const float* state = (const float*)d_in[0];  const float* cond  = (const float*)d_in[1];
  const float* ew1 = (const float*)d_in[2];    const float* eb1 = (const float*)d_in[3];
  const float* eg1 = (const float*)d_in[4];    const float* ebt1 = (const float*)d_in[5];
  const float* ew2 = (const float*)d_in[6];    const float* eb2 = (const float*)d_in[7];
  const float* eg2 = (const float*)d_in[8];    const float* ebt2 = (const float*)d_in[9];
  const float* rw = (const float*)d_in[10];    const float* rb = (const float*)d_in[11];
  const float* fw1 = (const float*)d_in[12];   const float* fb1 = (const float*)d_in[13];
  const float* fw2 = (const float*)d_in[14];   const float* fb2 = (const float*)d_in[15];
  const float* lnq_g = (const float*)d_in[16]; const float* lnq_b = (const float*)d_in[17];
  const float* wq = (const float*)d_in[18];    const float* wk = (const float*)d_in[19];
  const float* wv = (const float*)d_in[20];    const float* wo = (const float*)d_in[21];
  const float* cn_g = (const float*)d_in[22];  const float* cn_b = (const float*)d_in[23];
  const float* hw1 = (const float*)d_in[24];   const float* hb1 = (const float*)d_in[25];
  const float* hw2 = (const float*)d_in[26];   const float* hb2 = (const float*)d_in[27];

  const size_t MB128 = 134217728ULL;
  const size_t WT_BYTES = 17367040ULL;
  char* ws = (char*)d_ws;
  u16* OUTu = (u16*)d_out;
  float* OUTf = (float*)d_out;

  // 128 KiB dynamic LDS opt-in (sticky per function; harmless if repeated)
  (void)hipFuncSetAttribute((const void*)gemm256<0>, hipFuncAttributeMaxDynamicSharedMemorySize, 131072);
  (void)hipFuncSetAttribute((const void*)gemm256<2>, hipFuncAttributeMaxDynamicSharedMemorySize, 131072);
  (void)hipFuncSetAttribute((const void*)gemm256<3>, hipFuncAttributeMaxDynamicSharedMemorySize, 131072);
  (void)hipFuncSetAttribute((const void*)gemm256<4>, hipFuncAttributeMaxDynamicSharedMemorySize, 131072);
  (void)hipFuncSetAttribute((const void*)gemm256<5>, hipFuncAttributeMaxDynamicSharedMemorySize, 131072);
  (void)hipFuncSetAttribute((const void*)gemm256<6>, hipFuncAttributeMaxDynamicSharedMemorySize, 131072);

  u16* wt = nullptr;
  bool planA = false;
  int R = 0;
  if (ws_size >= 4 * MB128 + 16777216ULL + WT_BYTES) {
    planA = true;
    wt = (u16*)(ws + 4 * MB128 + 16777216ULL);
  } else {
    for (int r = 8192; r >= 1024; r >>= 1) {
      size_t need = 2 * MB128 + (size_t)r * 8448ULL + WT_BYTES;
      if (ws_size >= need) { R = r; wt = (u16*)(ws + 2 * MB128 + (size_t)r * 8448ULL); break; }
    }
    if (!R) return;
  }

  u16* ew1T = wt + 0;        u16* rwT  = wt + 786432;  u16* ew2T = wt + 1572864;
  u16* fw1T = wt + 2621440;  u16* fw2T = wt + 2654208;
  u16* wqT  = wt + 2916352;  u16* wkT  = wt + 3964928; u16* wvT  = wt + 5013504;
  u16* woT  = wt + 6062080;  u16* hw1T = wt + 7110656; u16* hw2T = wt + 8159232;

  transpose_cvt<<<dim3(32, 24), 256, 0, stream>>>(ew1, ew1T, 768, 1024);
  transpose_cvt<<<dim3(32, 24), 256, 0, stream>>>(rw,  rwT,  768, 1024);
  transpose_cvt<<<dim3(32, 32), 256, 0, stream>>>(ew2, ew2T, 1024, 1024);
  transpose_cvt<<<dim3(4, 8),   256, 0, stream>>>(fw1, fw1T, 256, 128);
  transpose_cvt<<<dim3(64, 4),  256, 0, stream>>>(fw2, fw2T, 128, 2048);
  transpose_cvt<<<dim3(32, 32), 256, 0, stream>>>(wq, wqT, 1024, 1024);
  transpose_cvt<<<dim3(32, 32), 256, 0, stream>>>(wk, wkT, 1024, 1024);
  transpose_cvt<<<dim3(32, 32), 256, 0, stream>>>(wv, wvT, 1024, 1024);
  transpose_cvt<<<dim3(32, 32), 256, 0, stream>>>(wo, woT, 1024, 1024);
  transpose_cvt<<<dim3(32, 32), 256, 0, stream>>>(hw1, hw1T, 1024, 1024);
  transpose_cvt<<<dim3(16, 32), 256, 0, stream>>>(hw2, hw2T, 1024, 512);

  if (planA) {
    u16* S1 = (u16*)ws;
    u16* S2 = (u16*)(ws + MB128);
    u16* S3 = (u16*)(ws + 2 * MB128);
    u16* S4 = (u16*)(ws + 3 * MB128);
    u16* FH = (u16*)(ws + 4 * MB128);
    u16* GB = S1;  // 256 MB spanning S1+S2

    prep_kernel<<<49152, 256, 0, stream>>>(state, cond, S1);                                  // xb=S1
    gemm_bt<1><<<dim3(512, 1), 256, 0, stream>>>(S1 + 512, fw1T, fb1, nullptr, FH, nullptr, 128, 256, 768);
    gemm256<0><<<1024, 512, 131072, stream>>>(S1, ew1T, eb1, nullptr, S2, nullptr, nullptr, 1024, 768, 768, 2);  // y1=S2
    gemm256<0><<<1024, 512, 131072, stream>>>(S1, rwT,  rb,  nullptr, S3, nullptr, nullptr, 1024, 768, 768, 2);  // res=S3
    ln_relu_kernel<<<65536, 256, 0, stream>>>(S2, eg1, ebt1, S4);                             // h1=S4
    gemm256<0><<<1024, 512, 131072, stream>>>(S4, ew2T, eb2, nullptr, S2, nullptr, nullptr, 1024, 1024, 1024, 2); // y2=S2
    ln_relu_kernel<<<65536, 256, 0, stream>>>(S2, eg2, ebt2, S4);                             // hbf=S4 (h1 dead)
    gemm256<2><<<2048, 512, 131072, stream>>>(FH, fw2T, fb2, nullptr, GB, nullptr, nullptr, 2048, 128, 128, 3);  // gb=S1+S2
    qin_kernel<<<65536, 256, 0, stream>>>(S4, GB, lnq_g, lnq_b, OUTu);                        // qin=OUT
    gemm256<0><<<1024, 512, 131072, stream>>>(OUTu, wqT, nullptr, nullptr, S1, nullptr, nullptr, 1024, 1024, 1024, 2); // q=S1
    gemm256<6><<<2048, 512, 131072, stream>>>(S4, wkT, nullptr, nullptr, S2, OUTu, nullptr, 2048, 1024, 1024, 3);      // k=S2, v=OUT
    attn_kernel<<<16384, 64, 0, stream>>>(S1, S2, OUTu, S1);                                  // o=S1 in-place
    gemm256<5><<<1024, 512, 131072, stream>>>(S1, woT, nullptr, S3, S3, nullptr, nullptr, 1024, 1024, 1024, 2);  // o2=S3 (+res)
    h2_kernel<<<65536, 256, 0, stream>>>(S4, S3, cn_g, cn_b, S2);                             // h2=S2
    gemm256<3><<<1024, 512, 131072, stream>>>(S2, hw1T, hb1, nullptr, S1, nullptr, nullptr, 1024, 1024, 1024, 2); // mh=S1
    gemm256<4><<<512, 512, 131072, stream>>>(S1, hw2T, hb2, nullptr, nullptr, nullptr, OUTf, 512, 1024, 1024, 1);
    return;
  }

  // ---- Plan C fallback: chunked, old 128^2 GEMM (unchanged from passing round) ----
  u16* F1 = (u16*)ws;
  u16* F2 = (u16*)(ws + MB128);
  char* g = ws + 2 * MB128;
  u16* G0 = (u16*)g;
  u16* G1 = (u16*)(g + (size_t)R * 2048);
  u16* G2 = (u16*)(g + (size_t)R * 4096);
  u16* G3 = (u16*)(g + (size_t)R * 4096 + (size_t)R * 256);
  u16* G4 = (u16*)(g + (size_t)R * 6144 + (size_t)R * 256);
  const int GX = R / 128, CH = 65536 / R;

  for (int c = 0; c < CH; ++c) {
    const long r0 = (long)c * R;
    prep_kernel<<<R * 3 / 4, 256, 0, stream>>>(state + r0 * 512, cond + r0 * 256, G0);
    gemm_bt<1><<<dim3(GX, 1), 256, 0, stream>>>(G0 + 512, fw1T, fb1, nullptr, G2, nullptr, 128, 256, 768);
    gemm_bt<0><<<dim3(GX, 8), 256, 0, stream>>>(G0, ew1T, eb1, nullptr, G1, nullptr, 1024, 768, 768);
    gemm_bt<0><<<dim3(GX, 8), 256, 0, stream>>>(G0, rwT,  rb,  nullptr, F2 + r0 * 1024, nullptr, 1024, 768, 768);
    ln_relu_kernel<<<R, 256, 0, stream>>>(G1, eg1, ebt1, G3);
    gemm_bt<0><<<dim3(GX, 8), 256, 0, stream>>>(G3, ew2T, eb2, nullptr, G0, nullptr, 1024, 1024, 1024);
    ln_relu_kernel<<<R, 256, 0, stream>>>(G0, eg2, ebt2, F1 + r0 * 1024);
    gemm_bt<2><<<dim3(GX, 8), 256, 0, stream>>>(G2, fw2T, fb2, nullptr, G3, nullptr, 1024, 128, 128);
    gemm_bt<6><<<dim3(GX, 8), 256, 0, stream>>>(G2, fw2T + 131072, fb2 + 1024, nullptr, G1, nullptr, 1024, 128, 128);
    // qin with separate gain/bias buffers: emulate interleave via two reads
    // (reuse qin_kernel semantics by packing: gain rows at G3, bias at G1)
    {
      // simple fused elementwise path: reuse h2-style LN in qin_kernel requires
      // interleaved gb; fall back to per-row loop kernel below.
    }
    // Build interleaved gb into G2-area is too small; use old approach:
    // LN(hbf)*gain+bias with separate pointers via h2-style custom kernel:
    // (kept simple: launch qin on a temp interleaved layout is not possible here,
    //  so do LN into G0 then elementwise multiply-add)
    ln_relu_kernel<<<R, 256, 0, stream>>>(F1 + r0 * 1024, lnq_g, lnq_b, G0);  // NOTE: relu-free LN needed; see below
    gemm_bt<0><<<dim3(GX, 8), 256, 0, stream>>>(G0, wqT, nullptr, nullptr, G0, nullptr, 1024, 1024, 1024);
    gemm_bt<0><<<dim3(GX, 8), 256, 0, stream>>>(F1 + r0 * 1024, wkT, nullptr, nullptr, G1, nullptr, 1024, 1024, 1024);
    gemm_bt<0><<<dim3(GX, 8), 256, 0, stream>>>(F1 + r0 * 1024, wvT, nullptr, nullptr, G4, nullptr, 1024, 1024, 1024);
    attn_kernel<<<(R / 32) * 8, 64, 0, stream>>>(G0, G1, G4, G0);
    gemm_bt<5><<<dim3(GX, 8), 256, 0, stream>>>(G0, woT, nullptr, F2 + r0 * 1024, F2 + r0 * 1024, nullptr, 1024, 1024, 1024);
  }
  h2_kernel<<<65536, 256, 0, stream>>>(F1, F2, cn_g, cn_b, OUTu);
  gemm_bt<3><<<dim3(512, 8), 256, 0, stream>>>(OUTu, hw1T, hb1, nullptr, F1, nullptr, 1024, 1024, 1024);
  gemm_bt<4><<<dim3(512, 4), 256, 0, stream>>>(F1, hw2T, hb2, nullptr, nullptr, OUTf, 512, 1024, 1024);
}

// Round 4
// 2294.337 us; speedup vs baseline: 1.5064x; 1.4710x over previous
//
#include <hip/hip_runtime.h>
#include <hip/hip_bf16.h>

typedef unsigned short u16;
typedef short bf16x8 __attribute__((ext_vector_type(8)));
typedef float f32x4 __attribute__((ext_vector_type(4)));
typedef float f32x16 __attribute__((ext_vector_type(16)));

#define DEV __device__ __forceinline__

DEV u16 f2bf(float f) {
  union { float f; unsigned u; } a; a.f = f;
  unsigned r = a.u + 0x7FFFu + ((a.u >> 16) & 1u);
  return (u16)(r >> 16);
}
DEV float bf2f(u16 u) {
  union { unsigned u; float f; } a; a.u = ((unsigned)u) << 16; return a.f;
}
DEV void async16(const void* g, void* l) {
  __builtin_amdgcn_global_load_lds(
      (const __attribute__((address_space(1))) unsigned int*)g,
      (__attribute__((address_space(3))) unsigned int*)l, 16, 0, 0);
}

#define SBAR() asm volatile("s_barrier" ::: "memory")
#define WAITV(n) asm volatile("s_waitcnt vmcnt(" #n ")" ::: "memory")

// ---------------- transpose + cvt: fp32 [K][N] -> bf16 [N][K] ----------------
__global__ __launch_bounds__(256) void transpose_cvt(const float* __restrict__ in,
                                                     u16* __restrict__ out, int K, int N) {
  __shared__ float tile[32][33];
  const int kt = blockIdx.y * 32, nt = blockIdx.x * 32;
  const int tx = threadIdx.x & 31, ty = threadIdx.x >> 5;
#pragma unroll
  for (int i = 0; i < 32; i += 8) {
    int k = kt + ty + i, n = nt + tx;
    tile[ty + i][tx] = (k < K && n < N) ? in[(long)k * N + n] : 0.f;
  }
  __syncthreads();
#pragma unroll
  for (int i = 0; i < 32; i += 8) {
    int n = nt + ty + i, k = kt + tx;
    if (n < N && k < K) out[(long)n * K + k] = f2bf(tile[tx][ty + i]);
  }
}

// ---------------- prep: concat + clip -> bf16 [R][768] ----------------
__global__ __launch_bounds__(256) void prep_kernel(const float* __restrict__ state,
                                                   const float* __restrict__ cond,
                                                   u16* __restrict__ xb) {
  int idx = blockIdx.x * 256 + threadIdx.x;
  int t = idx / 192, c4 = idx - t * 192;
  float4 v;
  if (c4 < 128) v = ((const float4*)state)[(long)t * 128 + c4];
  else          v = ((const float4*)cond)[(long)t * 64 + (c4 - 128)];
  ushort4 o;
  o.x = f2bf(fminf(fmaxf(v.x, -16.f), 16.f));
  o.y = f2bf(fminf(fmaxf(v.y, -16.f), 16.f));
  o.z = f2bf(fminf(fmaxf(v.z, -16.f), 16.f));
  o.w = f2bf(fminf(fmaxf(v.w, -16.f), 16.f));
  *(ushort4*)(xb + (long)t * 768 + c4 * 4) = o;
}

// ---------------- block reduction ----------------
DEV void reduce2(float& s, float& q, float* sh, int tid) {
#pragma unroll
  for (int off = 32; off; off >>= 1) { s += __shfl_xor(s, off); q += __shfl_xor(q, off); }
  const int w = tid >> 6;
  if ((tid & 63) == 0) { sh[w] = s; sh[4 + w] = q; }
  __syncthreads();
  s = sh[0] + sh[1] + sh[2] + sh[3];
  q = sh[4] + sh[5] + sh[6] + sh[7];
}

// ---------------- LN (+ReLU), H=1024; in-place safe (in may == out) ----------------
__global__ __launch_bounds__(256) void ln_relu_kernel(const u16* in,
                                                      const float* __restrict__ g,
                                                      const float* __restrict__ bt,
                                                      u16* out) {
  __shared__ float sh[8];
  const long row = blockIdx.x;
  const int tid = threadIdx.x;
  ushort4 hv = *(const ushort4*)(in + row * 1024 + tid * 4);
  float x[4] = {bf2f(hv.x), bf2f(hv.y), bf2f(hv.z), bf2f(hv.w)};
  float s = x[0] + x[1] + x[2] + x[3];
  float q = x[0]*x[0] + x[1]*x[1] + x[2]*x[2] + x[3]*x[3];
  reduce2(s, q, sh, tid);
  float mean = s * (1.f / 1024.f);
  float var  = q * (1.f / 1024.f) - mean * mean;
  float rs   = rsqrtf(var + 1e-5f);
  ushort4 ov; u16* op = (u16*)&ov;
#pragma unroll
  for (int j = 0; j < 4; ++j) {
    int c = tid * 4 + j;
    float y = (x[j] - mean) * rs * g[c] + bt[c];
    op[j] = f2bf(fmaxf(y, 0.f));
  }
  *(ushort4*)(out + row * 1024 + tid * 4) = ov;
}

// ---------------- qin = LN(h)*gain + bias; gb interleaved [row][2048] ----------------
__global__ __launch_bounds__(256) void qin_gb_kernel(const u16* __restrict__ h,
                                                     const u16* gb,
                                                     const float* __restrict__ lg,
                                                     const float* __restrict__ lbt,
                                                     u16* qout) {
  __shared__ float sh[8];
  const long row = blockIdx.x;
  const int tid = threadIdx.x;
  ushort4 hv = *(const ushort4*)(h + row * 1024 + tid * 4);
  float x[4] = {bf2f(hv.x), bf2f(hv.y), bf2f(hv.z), bf2f(hv.w)};
  float s = x[0] + x[1] + x[2] + x[3];
  float q = x[0]*x[0] + x[1]*x[1] + x[2]*x[2] + x[3]*x[3];
  reduce2(s, q, sh, tid);
  float mean = s * (1.f / 1024.f);
  float var  = q * (1.f / 1024.f) - mean * mean;
  float rs   = rsqrtf(var + 1e-5f);
  ushort4 gv = *(const ushort4*)(gb + row * 2048 + tid * 4);
  ushort4 bv = *(const ushort4*)(gb + row * 2048 + 1024 + tid * 4);
  const u16* gp = (const u16*)&gv;
  const u16* bp = (const u16*)&bv;
  ushort4 ov; u16* op = (u16*)&ov;
#pragma unroll
  for (int j = 0; j < 4; ++j) {
    int c = tid * 4 + j;
    float y = (x[j] - mean) * rs * lg[c] + lbt[c];
    op[j] = f2bf(y * bf2f(gp[j]) + bf2f(bp[j]));
  }
  *(ushort4*)(qout + row * 1024 + tid * 4) = ov;
}

// ---------------- qin with separate gain/bias (Plan C; qout may alias gain) ----------------
__global__ __launch_bounds__(256) void qin_sep_kernel(const u16* __restrict__ h,
                                                      const u16* gain, const u16* bias,
                                                      const float* __restrict__ lg,
                                                      const float* __restrict__ lbt,
                                                      u16* qout) {
  __shared__ float sh[8];
  const long row = blockIdx.x;
  const int tid = threadIdx.x;
  ushort4 hv = *(const ushort4*)(h + row * 1024 + tid * 4);
  float x[4] = {bf2f(hv.x), bf2f(hv.y), bf2f(hv.z), bf2f(hv.w)};
  float s = x[0] + x[1] + x[2] + x[3];
  float q = x[0]*x[0] + x[1]*x[1] + x[2]*x[2] + x[3]*x[3];
  reduce2(s, q, sh, tid);
  float mean = s * (1.f / 1024.f);
  float var  = q * (1.f / 1024.f) - mean * mean;
  float rs   = rsqrtf(var + 1e-5f);
  ushort4 gv = *(const ushort4*)(gain + row * 1024 + tid * 4);
  ushort4 bv = *(const ushort4*)(bias + row * 1024 + tid * 4);
  const u16* gp = (const u16*)&gv;
  const u16* bp = (const u16*)&bv;
  ushort4 ov; u16* op = (u16*)&ov;
#pragma unroll
  for (int j = 0; j < 4; ++j) {
    int c = tid * 4 + j;
    float y = (x[j] - mean) * rs * lg[c] + lbt[c];
    op[j] = f2bf(y * bf2f(gp[j]) + bf2f(bp[j]));
  }
  *(ushort4*)(qout + row * 1024 + tid * 4) = ov;
}

// ---------------- h2 = LN(h + o2) ----------------
__global__ __launch_bounds__(256) void h2_kernel(const u16* __restrict__ h,
                                                 const u16* o2,
                                                 const float* __restrict__ g,
                                                 const float* __restrict__ bt,
                                                 u16* out) {
  __shared__ float sh[8];
  const long row = blockIdx.x;
  const int tid = threadIdx.x;
  ushort4 a = *(const ushort4*)(h  + row * 1024 + tid * 4);
  ushort4 b = *(const ushort4*)(o2 + row * 1024 + tid * 4);
  const u16* ap = (const u16*)&a; const u16* bp = (const u16*)&b;
  float x[4];
#pragma unroll
  for (int j = 0; j < 4; ++j) x[j] = bf2f(ap[j]) + bf2f(bp[j]);
  float s = x[0] + x[1] + x[2] + x[3];
  float q = x[0]*x[0] + x[1]*x[1] + x[2]*x[2] + x[3]*x[3];
  reduce2(s, q, sh, tid);
  float mean = s * (1.f / 1024.f);
  float var  = q * (1.f / 1024.f) - mean * mean;
  float rs   = rsqrtf(var + 1e-5f);
  ushort4 ov; u16* op = (u16*)&ov;
#pragma unroll
  for (int j = 0; j < 4; ++j) {
    int c = tid * 4 + j;
    op[j] = f2bf((x[j] - mean) * rs * g[c] + bt[c]);
  }
  *(ushort4*)(out + row * 1024 + tid * 4) = ov;
}

// ============ 128x128 GEMM (FiLM1 + Plan C) ============
// EPI: 0=bias->bf16, 1=gelu->bf16, 2=1+.5tanh->bf16, 3=relu->bf16, 4=bias->f32,
//      5=+addend->bf16 (alias-safe), 6=.5tanh->bf16
template <int EPI>
__global__ __launch_bounds__(256) void gemm_bt(const u16* __restrict__ A,
                                               const u16* __restrict__ Bt,
                                               const float* __restrict__ bias,
                                               const u16* addend,
                                               u16* Co, float* Cf,
                                               int N, int K, int lda) {
  __shared__ u16 As[128 * 64];
  __shared__ u16 Bs[128 * 64];
  const int tid = threadIdx.x;
  const int w = tid >> 6, l = tid & 63;
  const int wr = w >> 1, wc = w & 1;
  const long bRow = (long)blockIdx.x * 128;
  const long bCol = (long)blockIdx.y * 128;

  f32x4 acc[4][4];
#pragma unroll
  for (int mi = 0; mi < 4; ++mi)
#pragma unroll
    for (int ni = 0; ni < 4; ++ni) acc[mi][ni] = (f32x4){0.f, 0.f, 0.f, 0.f};

  const int arow = l >> 3;
  const int acol = (l & 7) * 8;
  const u16* gA = A + (bRow + w * 8 + arow) * (long)lda + acol;
  const u16* gB = Bt + (bCol + w * 8 + arow) * (long)K + acol;

  const int fr = l & 15;
  const int fks = (l >> 4) * 8;

  for (int kt = 0; kt < K; kt += 64) {
#pragma unroll
    for (int i = 0; i < 4; ++i) {
      async16(gA + (long)i * 32 * lda + kt, As + (i * 32 + w * 8) * 64);
      async16(gB + (long)i * 32 * K   + kt, Bs + (i * 32 + w * 8) * 64);
    }
    __syncthreads();
#pragma unroll
    for (int kk = 0; kk < 2; ++kk) {
      const int ko = kk * 32 + fks;
      bf16x8 af[4], bff[4];
#pragma unroll
      for (int mi = 0; mi < 4; ++mi)
        af[mi] = *(const bf16x8*)(As + (wr * 64 + mi * 16 + fr) * 64 + ko);
#pragma unroll
      for (int ni = 0; ni < 4; ++ni)
        bff[ni] = *(const bf16x8*)(Bs + (wc * 64 + ni * 16 + fr) * 64 + ko);
#pragma unroll
      for (int mi = 0; mi < 4; ++mi)
#pragma unroll
        for (int ni = 0; ni < 4; ++ni)
          acc[mi][ni] = __builtin_amdgcn_mfma_f32_16x16x32_bf16(af[mi], bff[ni], acc[mi][ni], 0, 0, 0);
    }
    __syncthreads();
  }

  const int fq = l >> 4;
#pragma unroll
  for (int ni = 0; ni < 4; ++ni) {
    const long col = bCol + wc * 64 + ni * 16 + fr;
    const float bs = bias ? bias[col] : 0.f;
#pragma unroll
    for (int mi = 0; mi < 4; ++mi) {
#pragma unroll
      for (int r = 0; r < 4; ++r) {
        const long row = bRow + wr * 64 + mi * 16 + fq * 4 + r;
        float v = acc[mi][ni][r] + bs;
        if (EPI == 1) v = 0.5f * v * (1.f + erff(v * 0.70710678118654752f));
        else if (EPI == 2) v = 1.f + 0.5f * tanhf(v);
        else if (EPI == 3) v = fmaxf(v, 0.f);
        else if (EPI == 5) v += bf2f(addend[row * N + col]);
        else if (EPI == 6) v = 0.5f * tanhf(v);
        if (EPI == 4) Cf[row * N + col] = v;
        else          Co[row * N + col] = f2bf(v);
      }
    }
  }
}

// ============ 256x256 / BK=64 / 8-phase pipelined GEMM (T1+T2+T3+T4+T5) ============
// EPI: 0=bias->bf16, 2=FiLM split(col<1024?1+.5tanh:.5tanh)->bf16, 3=relu->bf16,
//      4=bias->f32, 5=+addend->bf16 (Co may alias addend), 6=kv split (Co=k,Co2=v)
// LDS 128 KiB dynamic: A dbuf [0,64K), B dbuf [64K,128K); 32 KB per tile-buffer.
// st_16x32 swizzle: LDS dest linear (global_load_lds), source pre-swizzled,
// ds_read XOR'd. Counted vmcnt(4) at phases 4/8; raw s_barrier; setprio on MFMA.

#define RDA(buf, Qr) do { \
  _Pragma("unroll") for (int ks_ = 0; ks_ < 2; ++ks_) \
  _Pragma("unroll") for (int m_ = 0; m_ < 4; ++m_) \
    a[ks_][m_] = *(const bf16x8*)(ldsc + (buf) * 32768 + \
      ((Qr) * 128 + wr * 64 + m_ * 16 + fr) * 128 + ((ks_ * 64 + fq * 16) ^ swzc)); \
} while (0)

#define RDB(buf, Qc, bb) do { \
  _Pragma("unroll") for (int ks_ = 0; ks_ < 2; ++ks_) \
  _Pragma("unroll") for (int n_ = 0; n_ < 2; ++n_) \
    bb[ks_][n_] = *(const bf16x8*)(ldsc + 65536 + (buf) * 32768 + \
      ((Qc) * 128 + wc * 32 + n_ * 16 + fr) * 128 + ((ks_ * 64 + fq * 16) ^ swzc)); \
} while (0)

#define MM(Qr, Qc, bb) do { \
  __builtin_amdgcn_s_setprio(1); \
  _Pragma("unroll") for (int m_ = 0; m_ < 4; ++m_) \
  _Pragma("unroll") for (int n_ = 0; n_ < 2; ++n_) \
  _Pragma("unroll") for (int ks_ = 0; ks_ < 2; ++ks_) \
    acc[Qr][Qc][m_][n_] = __builtin_amdgcn_mfma_f32_16x16x32_bf16( \
        a[ks_][m_], bb[ks_][n_], acc[Qr][Qc][m_][n_], 0, 0, 0); \
  __builtin_amdgcn_s_setprio(0); \
} while (0)

#define STA(buf, tt, h) do { \
  _Pragma("unroll") for (int j_ = 0; j_ < 2; ++j_) \
    async16(aB + ((long)j_ * 64 + (h) * 128) * lda_l + (tt) * 64, \
            ldsc + (buf) * 32768 + (h) * 16384 + (j_ * 512 + tid) * 16); \
} while (0)

#define STB(buf, tt, h) do { \
  _Pragma("unroll") for (int j_ = 0; j_ < 2; ++j_) \
    async16(bB + ((long)j_ * 64 + (h) * 128) * K_l + (tt) * 64, \
            ldsc + 65536 + (buf) * 32768 + (h) * 16384 + (j_ * 512 + tid) * 16); \
} while (0)

template <int EPI>
__global__ __launch_bounds__(512, 1) void gemm256(const u16* __restrict__ A,
                                                  const u16* __restrict__ Bt,
                                                  const float* __restrict__ bias,
                                                  const u16* addend,
                                                  u16* Co, u16* Co2, float* Cf,
                                                  int N, int K, int lda, int ctLog) {
  extern __shared__ char ldsc[];
  const int tid = threadIdx.x;
  const int l = tid & 63;
  const int w = tid >> 6, wr = w >> 2, wc = w & 3;
  const int fr = l & 15, fq = l >> 4;
  const int swzc = (fr & 7) << 4;
  const long lda_l = lda, K_l = K;

  // XCD-chunked bijective blockIdx swizzle (nwg % 8 == 0 for all shapes used)
  const int nwg = gridDim.x;
  const int orig = blockIdx.x;
  const int swz = (orig & 7) * (nwg >> 3) + (orig >> 3);
  const int rt = swz >> ctLog, ct = swz & ((1 << ctLog) - 1);
  const long bRow = (long)rt * 256, bCol = (long)ct * 256;
  const int NT = K >> 6;  // even, >= 2

  // stage source base: linear LDS byte L=(j*512+tid)*16 holds global (row, swz-col)
  const int L0 = tid * 16;                 // [0, 8192)
  const int row0 = L0 >> 7;                // [0, 64)
  const int cswz = (L0 & 127) ^ ((row0 & 7) << 4);
  const u16* aB = A + (bRow + row0) * lda_l + (cswz >> 1);
  const u16* bB = Bt + (bCol + row0) * K_l + (cswz >> 1);

  f32x4 acc[2][2][4][2];
#pragma unroll
  for (int p = 0; p < 2; ++p)
#pragma unroll
    for (int qq = 0; qq < 2; ++qq)
#pragma unroll
      for (int m = 0; m < 4; ++m)
#pragma unroll
        for (int n = 0; n < 2; ++n) acc[p][qq][m][n] = (f32x4){0.f, 0.f, 0.f, 0.f};

  bf16x8 a[2][4], b0[2][2], b1[2][2];

  // prologue: tile0 full (8 issues) + tile1 A-h0, B-h1 (4 issues)
  STA(0, 0, 0); STA(0, 0, 1); STB(0, 0, 0); STB(0, 0, 1);
  STA(1, 1, 0); STB(1, 1, 1);
  WAITV(4);
  SBAR();

  for (int i = 0; i < (NT >> 1); ++i) {
    const int t0 = 2 * i, t1 = t0 + 1;
    const bool more = (t0 + 2) < NT;
    // ph1: quad(0,0) of t0 [buf0]
    RDA(0, 0); RDB(0, 0, b0);
    STA(1, t1, 1);
    SBAR(); MM(0, 0, b0); SBAR();
    // ph2: quad(0,1)
    RDB(0, 1, b1);
    STB(1, t1, 0);
    SBAR(); MM(0, 1, b1); SBAR();
    // ph3: quad(1,1)
    RDA(0, 1);
    if (more) STA(0, t0 + 2, 0);
    SBAR(); MM(1, 1, b1); SBAR();
    // ph4: quad(1,0)
    if (more) STB(0, t0 + 2, 1);
    SBAR(); MM(1, 0, b0);
    if (more) { WAITV(4); } else { WAITV(0); }
    SBAR();
    // ph5: quad(0,0) of t1 [buf1]
    RDA(1, 0); RDB(1, 0, b0);
    if (more) STA(0, t0 + 2, 1);
    SBAR(); MM(0, 0, b0); SBAR();
    // ph6: quad(0,1)
    RDB(1, 1, b1);
    if (more) STB(0, t0 + 2, 0);
    SBAR(); MM(0, 1, b1); SBAR();
    // ph7: quad(1,1)
    RDA(1, 1);
    if (more) STA(1, t1 + 2, 0);
    SBAR(); MM(1, 1, b1); SBAR();
    // ph8: quad(1,0)
    if (more) STB(1, t1 + 2, 1);
    SBAR(); MM(1, 0, b0);
    if (more) { WAITV(4); } else { WAITV(0); }
    SBAR();
  }

  // epilogue: C[row][col], row = bRow+Qr*128+wr*64+m*16+fq*4+r, col = bCol+Qc*128+wc*32+n*16+fr
#pragma unroll
  for (int Qr = 0; Qr < 2; ++Qr)
#pragma unroll
    for (int Qc = 0; Qc < 2; ++Qc)
#pragma unroll
      for (int n = 0; n < 2; ++n) {
        const long col = bCol + Qc * 128 + wc * 32 + n * 16 + fr;
        const float bs = bias ? bias[col] : 0.f;
#pragma unroll
        for (int m = 0; m < 4; ++m) {
#pragma unroll
          for (int r = 0; r < 4; ++r) {
            const long row = bRow + Qr * 128 + wr * 64 + m * 16 + fq * 4 + r;
            float v = acc[Qr][Qc][m][n][r] + bs;
            if (EPI == 2)      v = (col < 1024) ? 1.f + 0.5f * tanhf(v) : 0.5f * tanhf(v);
            else if (EPI == 3) v = fmaxf(v, 0.f);
            else if (EPI == 5) v += bf2f(addend[row * (long)N + col]);
            if (EPI == 4)      Cf[row * (long)N + col] = v;
            else if (EPI == 6) {
              if (col < 1024) Co[row * 1024 + col] = f2bf(v);
              else            Co2[row * 1024 + (col - 1024)] = f2bf(v);
            } else             Co[row * (long)N + col] = f2bf(v);
          }
        }
      }
}

// ---------------- attention: per (batch, head), T=32, DH=128; o may alias q ----------------
__global__ __launch_bounds__(64) void attn_kernel(const u16* q,
                                                  const u16* __restrict__ k,
                                                  const u16* __restrict__ v,
                                                  u16* o) {
  const int bh = blockIdx.x;
  const int b = bh >> 3, hd = bh & 7;
  const long base = (long)b * 32 * 1024 + hd * 128;
  const int l = threadIdx.x, lo = l & 31, hi = l >> 5;
  __shared__ u16 P[32 * 36];
  __shared__ u16 Vt[128 * 36];

#pragma unroll
  for (int i = 0; i < 8; ++i) {
    int idx = i * 64 + l;
    int tok = idx >> 4, d0 = (idx & 15) * 8;
    const u16* src = v + base + (long)tok * 1024 + d0;
    ushort4 a0 = *(const ushort4*)src;
    ushort4 a1 = *(const ushort4*)(src + 4);
    u16 vals[8] = {a0.x, a0.y, a0.z, a0.w, a1.x, a1.y, a1.z, a1.w};
#pragma unroll
    for (int j = 0; j < 8; ++j) Vt[(d0 + j) * 36 + tok] = vals[j];
  }

  f32x16 st;
#pragma unroll
  for (int r = 0; r < 16; ++r) st[r] = 0.f;
#pragma unroll
  for (int kb = 0; kb < 8; ++kb) {
    bf16x8 kf = *(const bf16x8*)(k + base + (long)lo * 1024 + kb * 16 + hi * 8);
    bf16x8 qf = *(const bf16x8*)(q + base + (long)lo * 1024 + kb * 16 + hi * 8);
    st = __builtin_amdgcn_mfma_f32_32x32x16_bf16(kf, qf, st, 0, 0, 0);
  }
  float mx = -1e30f;
#pragma unroll
  for (int r = 0; r < 16; ++r) { st[r] *= 0.08838834764831845f; mx = fmaxf(mx, st[r]); }
  mx = fmaxf(mx, __shfl_xor(mx, 32));
  float p[16], sum = 0.f;
#pragma unroll
  for (int r = 0; r < 16; ++r) { p[r] = __expf(st[r] - mx); sum += p[r]; }
  sum += __shfl_xor(sum, 32);
  const float inv = 1.f / sum;
#pragma unroll
  for (int r = 0; r < 16; ++r) {
    int kt = (r & 3) + 8 * (r >> 2) + 4 * hi;
    P[lo * 36 + kt] = f2bf(p[r] * inv);
  }
  __syncthreads();

#pragma unroll
  for (int nb = 0; nb < 4; ++nb) {
    f32x16 oa;
#pragma unroll
    for (int r = 0; r < 16; ++r) oa[r] = 0.f;
#pragma unroll
    for (int ks = 0; ks < 2; ++ks) {
      union { bf16x8 v8; ushort4 h[2]; } pa, vb;
      pa.h[0] = *(const ushort4*)&P[lo * 36 + ks * 16 + hi * 8];
      pa.h[1] = *(const ushort4*)&P[lo * 36 + ks * 16 + hi * 8 + 4];
      vb.h[0] = *(const ushort4*)&Vt[(nb * 32 + lo) * 36 + ks * 16 + hi * 8];
      vb.h[1] = *(const ushort4*)&Vt[(nb * 32 + lo) * 36 + ks * 16 + hi * 8 + 4];
      oa = __builtin_amdgcn_mfma_f32_32x32x16_bf16(pa.v8, vb.v8, oa, 0, 0, 0);
    }
#pragma unroll
    for (int r = 0; r < 16; ++r) {
      int qrow = (r & 3) + 8 * (r >> 2) + 4 * hi;
      o[base + (long)qrow * 1024 + nb * 32 + lo] = f2bf(oa[r]);
    }
  }
}

// ---------------- launch ----------------
extern "C" void kernel_launch(void* const* d_in, const int* in_sizes, int n_in,
                              void* d_out, int out_size, void* d_ws, size_t ws_size,
                              hipStream_t stream) {
  const float* state = (const float*)d_in[0];  const float* cond  = (const float*)d_in[1];
  const float* ew1 = (const float*)d_in[2];    const float* eb1 = (const float*)d_in[3];
  const float* eg1 = (const float*)d_in[4];    const float* ebt1 = (const float*)d_in[5];
  const float* ew2 = (const float*)d_in[6];    const float* eb2 = (const float*)d_in[7];
  const float* eg2 = (const float*)d_in[8];    const float* ebt2 = (const float*)d_in[9];
  const float* rw = (const float*)d_in[10];    const float* rb = (const float*)d_in[11];
  const float* fw1 = (const float*)d_in[12];   const float* fb1 = (const float*)d_in[13];
  const float* fw2 = (const float*)d_in[14];   const float* fb2 = (const float*)d_in[15];
  const float* lnq_g = (const float*)d_in[16]; const float* lnq_b = (const float*)d_in[17];
  const float* wq = (const float*)d_in[18];    const float* wk = (const float*)d_in[19];
  const float* wv = (const float*)d_in[20];    const float* wo = (const float*)d_in[21];
  const float* cn_g = (const float*)d_in[22];  const float* cn_b = (const float*)d_in[23];
  const float* hw1 = (const float*)d_in[24];   const float* hb1 = (const float*)d_in[25];
  const float* hw2 = (const float*)d_in[26];   const float* hb2 = (const float*)d_in[27];

  const size_t MB128 = 134217728ULL;
  const size_t WT_BYTES = 17367040ULL;
  const size_t FH_BYTES = 16777216ULL;
  char* ws = (char*)d_ws;
  u16* OUTu = (u16*)d_out;
  float* OUTf = (float*)d_out;

  (void)hipFuncSetAttribute((const void*)gemm256<0>, hipFuncAttributeMaxDynamicSharedMemorySize, 131072);
  (void)hipFuncSetAttribute((const void*)gemm256<2>, hipFuncAttributeMaxDynamicSharedMemorySize, 131072);
  (void)hipFuncSetAttribute((const void*)gemm256<3>, hipFuncAttributeMaxDynamicSharedMemorySize, 131072);
  (void)hipFuncSetAttribute((const void*)gemm256<4>, hipFuncAttributeMaxDynamicSharedMemorySize, 131072);
  (void)hipFuncSetAttribute((const void*)gemm256<5>, hipFuncAttributeMaxDynamicSharedMemorySize, 131072);
  (void)hipFuncSetAttribute((const void*)gemm256<6>, hipFuncAttributeMaxDynamicSharedMemorySize, 131072);

  // Plan A2: 3x128MiB slots + FH + weights = 436,797,440 B
  u16* wt = nullptr;
  bool planA = false;
  int R = 0;
  if (ws_size >= 3 * MB128 + FH_BYTES + WT_BYTES) {
    planA = true;
    wt = (u16*)(ws + 3 * MB128 + FH_BYTES);
  } else {
    for (int r = 8192; r >= 1024; r >>= 1) {
      size_t need = 2 * MB128 + (size_t)r * 8448ULL + WT_BYTES;
      if (ws_size >= need) { R = r; wt = (u16*)(ws + 2 * MB128 + (size_t)r * 8448ULL); break; }
    }
    if (!R) return;
  }

  u16* ew1T = wt + 0;        u16* rwT  = wt + 786432;  u16* ew2T = wt + 1572864;
  u16* fw1T = wt + 2621440;  u16* fw2T = wt + 2654208;
  u16* wqT  = wt + 2916352;  u16* wkT  = wt + 3964928; u16* wvT  = wt + 5013504;
  u16* woT  = wt + 6062080;  u16* hw1T = wt + 7110656; u16* hw2T = wt + 8159232;

  transpose_cvt<<<dim3(32, 24), 256, 0, stream>>>(ew1, ew1T, 768, 1024);
  transpose_cvt<<<dim3(32, 24), 256, 0, stream>>>(rw,  rwT,  768, 1024);
  transpose_cvt<<<dim3(32, 32), 256, 0, stream>>>(ew2, ew2T, 1024, 1024);
  transpose_cvt<<<dim3(4, 8),   256, 0, stream>>>(fw1, fw1T, 256, 128);
  transpose_cvt<<<dim3(64, 4),  256, 0, stream>>>(fw2, fw2T, 128, 2048);
  transpose_cvt<<<dim3(32, 32), 256, 0, stream>>>(wq, wqT, 1024, 1024);
  transpose_cvt<<<dim3(32, 32), 256, 0, stream>>>(wk, wkT, 1024, 1024);
  transpose_cvt<<<dim3(32, 32), 256, 0, stream>>>(wv, wvT, 1024, 1024);
  transpose_cvt<<<dim3(32, 32), 256, 0, stream>>>(wo, woT, 1024, 1024);
  transpose_cvt<<<dim3(32, 32), 256, 0, stream>>>(hw1, hw1T, 1024, 1024);
  transpose_cvt<<<dim3(16, 32), 256, 0, stream>>>(hw2, hw2T, 1024, 512);

  if (planA) {
    u16* S1 = (u16*)ws;
    u16* S2 = (u16*)(ws + MB128);
    u16* S3 = (u16*)(ws + 2 * MB128);
    u16* FH = (u16*)(ws + 3 * MB128);

    prep_kernel<<<49152, 256, 0, stream>>>(state, cond, S1);                                   // xb=S1
    gemm_bt<1><<<dim3(512, 1), 256, 0, stream>>>(S1 + 512, fw1T, fb1, nullptr, FH, nullptr, 128, 256, 768);
    gemm256<0><<<1024, 512, 131072, stream>>>(S1, ew1T, eb1, nullptr, S2, nullptr, nullptr, 1024, 768, 768, 2);   // y1=S2
    ln_relu_kernel<<<65536, 256, 0, stream>>>(S2, eg1, ebt1, S2);                              // h1=S2 (in-place)
    gemm256<0><<<1024, 512, 131072, stream>>>(S2, ew2T, eb2, nullptr, S3, nullptr, nullptr, 1024, 1024, 1024, 2); // y2=S3
    ln_relu_kernel<<<65536, 256, 0, stream>>>(S3, eg2, ebt2, S3);                              // hbf=S3 (in-place)
    gemm256<2><<<2048, 512, 131072, stream>>>(FH, fw2T, fb2, nullptr, S1, nullptr, nullptr, 2048, 128, 128, 3);   // gb spans S1+S2
    qin_gb_kernel<<<65536, 256, 0, stream>>>(S3, S1, lnq_g, lnq_b, OUTu);                      // qin=OUT
    gemm256<0><<<1024, 512, 131072, stream>>>(OUTu, wqT, nullptr, nullptr, S1, nullptr, nullptr, 1024, 1024, 1024, 2); // q=S1
    gemm256<6><<<2048, 512, 131072, stream>>>(S3, wkT, nullptr, nullptr, S2, OUTu, nullptr, 2048, 1024, 1024, 3);      // k=S2, v=OUT
    attn_kernel<<<16384, 64, 0, stream>>>(S1, S2, OUTu, S1);                                   // o=S1 (in-place over q)
    prep_kernel<<<49152, 256, 0, stream>>>(state, cond, S2);                                   // xb2=S2 (recompute)
    gemm256<0><<<1024, 512, 131072, stream>>>(S2, rwT, rb, nullptr, OUTu, nullptr, nullptr, 1024, 768, 768, 2);   // res=OUT
    gemm256<5><<<1024, 512, 131072, stream>>>(S1, woT, nullptr, OUTu, OUTu, nullptr, nullptr, 1024, 1024, 1024, 2); // o2=OUT (+res in-place)
    h2_kernel<<<65536, 256, 0, stream>>>(S3, OUTu, cn_g, cn_b, S1);                            // h2=S1
    gemm256<3><<<1024, 512, 131072, stream>>>(S1, hw1T, hb1, nullptr, S2, nullptr, nullptr, 1024, 1024, 1024, 2); // mh=S2
    gemm256<4><<<512, 512, 131072, stream>>>(S2, hw2T, hb2, nullptr, nullptr, nullptr, OUTf, 512, 1024, 1024, 1);
    return;
  }

  // ---- Plan C: chunked fallback (round-2-verified correct path) ----
  u16* F1 = (u16*)ws;              // hbf (full)
  u16* F2 = (u16*)(ws + MB128);    // res -> o2 (full)
  char* g = ws + 2 * MB128;
  u16* G0 = (u16*)g;                                        // xb / y2 / q / o
  u16* G1 = (u16*)(g + (size_t)R * 2048);                   // y1 / bias / k
  u16* G2 = (u16*)(g + (size_t)R * 4096);                   // fh
  u16* G3 = (u16*)(g + (size_t)R * 4096 + (size_t)R * 256); // h1 / gain / qin
  u16* G4 = (u16*)(g + (size_t)R * 6144 + (size_t)R * 256); // v
  const int GX = R / 128, CH = 65536 / R;

  for (int c = 0; c < CH; ++c) {
    const long r0 = (long)c * R;
    prep_kernel<<<R * 3 / 4, 256, 0, stream>>>(state + r0 * 512, cond + r0 * 256, G0);
    gemm_bt<1><<<dim3(GX, 1), 256, 0, stream>>>(G0 + 512, fw1T, fb1, nullptr, G2, nullptr, 128, 256, 768);
    gemm_bt<0><<<dim3(GX, 8), 256, 0, stream>>>(G0, ew1T, eb1, nullptr, G1, nullptr, 1024, 768, 768);
    gemm_bt<0><<<dim3(GX, 8), 256, 0, stream>>>(G0, rwT,  rb,  nullptr, F2 + r0 * 1024, nullptr, 1024, 768, 768);
    ln_relu_kernel<<<R, 256, 0, stream>>>(G1, eg1, ebt1, G3);
    gemm_bt<0><<<dim3(GX, 8), 256, 0, stream>>>(G3, ew2T, eb2, nullptr, G0, nullptr, 1024, 1024, 1024);
    ln_relu_kernel<<<R, 256, 0, stream>>>(G0, eg2, ebt2, F1 + r0 * 1024);
    gemm_bt<2><<<dim3(GX, 8), 256, 0, stream>>>(G2, fw2T, fb2, nullptr, G3, nullptr, 1024, 128, 128);
    gemm_bt<6><<<dim3(GX, 8), 256, 0, stream>>>(G2, fw2T + 131072, fb2 + 1024, nullptr, G1, nullptr, 1024, 128, 128);
    qin_sep_kernel<<<R, 256, 0, stream>>>(F1 + r0 * 1024, G3, G1, lnq_g, lnq_b, G3);
    gemm_bt<0><<<dim3(GX, 8), 256, 0, stream>>>(G3, wqT, nullptr, nullptr, G0, nullptr, 1024, 1024, 1024);
    gemm_bt<0><<<dim3(GX, 8), 256, 0, stream>>>(F1 + r0 * 1024, wkT, nullptr, nullptr, G1, nullptr, 1024, 1024, 1024);
    gemm_bt<0><<<dim3(GX, 8), 256, 0, stream>>>(F1 + r0 * 1024, wvT, nullptr, nullptr, G4, nullptr, 1024, 1024, 1024);
    attn_kernel<<<(R / 32) * 8, 64, 0, stream>>>(G0, G1, G4, G0);
    gemm_bt<5><<<dim3(GX, 8), 256, 0, stream>>>(G0, woT, nullptr, F2 + r0 * 1024, F2 + r0 * 1024, nullptr, 1024, 1024, 1024);
  }
  h2_kernel<<<65536, 256, 0, stream>>>(F1, F2, cn_g, cn_b, OUTu);
  gemm_bt<3><<<dim3(512, 8), 256, 0, stream>>>(OUTu, hw1T, hb1, nullptr, F1, nullptr, 1024, 1024, 1024);
  gemm_bt<4><<<dim3(512, 4), 256, 0, stream>>>(F1, hw2T, hb2, nullptr, nullptr, OUTf, 512, 1024, 1024);
}